// Round 6
// baseline (392.416 us; speedup 1.0000x reference)
//
#include <hip/hip_runtime.h>
#include <math.h>

// Problem constants
#define B   16
#define N   128
#define E   4
#define H   64
#define M   64
#define IN_ 32
#define T   32
#define K1  128
#define K2  256
#define K3  128

typedef _Float16 f16;
typedef f16  f16x8 __attribute__((ext_vector_type(8)));
typedef f16  f16x4 __attribute__((ext_vector_type(4)));
typedef f16  f16x2 __attribute__((ext_vector_type(2)));
typedef float f32x4 __attribute__((ext_vector_type(4)));

#define MFMA16(a, b, c) __builtin_amdgcn_mfma_f32_16x16x32_f16(a, b, c, 0, 0, 0)

// fp16 weight pack offsets (halves)
#define OFF_W1T   0
#define OFF_W2T   32768
#define OFF_WE3H  65536
#define OFF_RI0   589824
#define OFF_RI1   602112
#define OFF_RI2   634880
#define OFF_RI3   667648
#define OFF_RJ0   671744
#define OFF_RJ1   679936
#define OFF_RJ2   712704
#define OFF_RJ3   745472
#define WPACK_SZ  749568

// R12: edge MFMA loops were L2-latency-exposed on weight loads (VGPR=76 shows
// compiler didn't hoist; L2 hit ~200cyc re-paid per s-iter). Hoist all W1t/W2t
// fragments into register arrays before each MFMA loop (burst prefetch).
// Geometry unchanged from R11 (best 387.7us).
union SmemU {
    struct { float xl[64][4]; f16 y1[64][136]; f16 y2[64][264]; } e;   // 52224
    union {
        struct { f16 Al[128][72]; f16 Bl[128][72]; } in;               // 36864
        f16 Ol[128][136];                                              // 34816
    } pg;
    struct { float prt[4][64]; float hsum[64]; float bias[64]; } bi;   // 1536
};

// -------------------------------------------------------------------------
// prep: pad h (fp32/fp16 + hin16) AND build fp16 weight pack. One launch.
__global__ __launch_bounds__(256) void prep_kernel(
    const float* __restrict__ h_in,
    const float* __restrict__ We1, const float* __restrict__ We2,
    const float* __restrict__ We3,
    const float* __restrict__ Wi0, const float* __restrict__ Wi1,
    const float* __restrict__ Wi2, const float* __restrict__ Wi3,
    const float* __restrict__ Wj0, const float* __restrict__ Wj1,
    const float* __restrict__ Wj2, const float* __restrict__ Wj3,
    float* __restrict__ h, f16* __restrict__ h16, f16* __restrict__ hin16,
    f16* __restrict__ wp) {
    int idx = blockIdx.x * 256 + threadIdx.x;
    if (idx < B * N * H) {
        int i  = idx & (H - 1);
        int bn = idx >> 6;
        float v = (i < IN_) ? h_in[bn * IN_ + i] : 0.f;
        h[idx] = v;
        h16[idx] = (f16)v;
        if (i < IN_) hin16[bn * IN_ + i] = (f16)v;
    }
    if (idx >= WPACK_SZ) return;
    if (idx < OFF_W2T) {                          // W1t [256][128]
        int j = idx >> 7, k = idx & 127;
        wp[idx] = (f16)We1[k * 256 + j];
    } else if (idx < OFF_WE3H) {                  // W2t [128][256]
        int t = idx - OFF_W2T;
        int j = t >> 8, k = t & 255;
        wp[idx] = (f16)We2[k * 128 + j];
    } else if (idx < OFF_RI0) {                   // We3h copy
        wp[idx] = (f16)We3[idx - OFF_WE3H];
    } else if (idx < OFF_RI1) {                   // Ri0 [128][96]
        int t = idx - OFF_RI0;
        int n = t / 96, c = t % 96;
        wp[idx] = (f16)Wi0[c * 128 + n];
    } else if (idx < OFF_RI2) {                   // Ri1 [256][128]
        int t = idx - OFF_RI1;
        int n = t >> 7, k = t & 127;
        wp[idx] = (f16)Wi1[k * 256 + n];
    } else if (idx < OFF_RI3) {                   // Ri2 [128][256]
        int t = idx - OFF_RI2;
        int n = t >> 8, k = t & 255;
        wp[idx] = (f16)Wi2[k * 128 + n];
    } else if (idx < OFF_RJ0) {                   // Ri3 [32][128]
        int t = idx - OFF_RI3;
        int n = t >> 7, k = t & 127;
        wp[idx] = (f16)Wi3[k * 32 + n];
    } else if (idx < OFF_RJ1) {                   // Rj0 [128][64]
        int t = idx - OFF_RJ0;
        int n = t >> 6, c = t & 63;
        wp[idx] = (f16)Wj0[c * 128 + n];
    } else if (idx < OFF_RJ2) {                   // Rj1 [256][128]
        int t = idx - OFF_RJ1;
        int n = t >> 7, k = t & 127;
        wp[idx] = (f16)Wj1[k * 256 + n];
    } else if (idx < OFF_RJ3) {                   // Rj2 [128][256]
        int t = idx - OFF_RJ2;
        int n = t >> 8, k = t & 255;
        wp[idx] = (f16)Wj2[k * 128 + n];
    } else {                                      // Rj3 [32][128]
        int t = idx - OFF_RJ3;
        int n = t >> 7, k = t & 127;
        wp[idx] = (f16)Wj3[k * 32 + n];
    }
}

// ===================== task bodies (256 threads) ===========================

__device__ void edge_body(SmemU& su, int tid, int tile,
                          const float* __restrict__ am,
                          const float* __restrict__ We0,
                          const float* __restrict__ be0,
                          const f16* __restrict__ W1t,
                          const float* __restrict__ be1,
                          const f16* __restrict__ W2t,
                          const float* __restrict__ be2,
                          f16* __restrict__ f) {
    int lane = tid & 63, wv = tid >> 6;
    long long g0 = (long long)tile * 64;

    ((float*)su.e.xl)[tid] = am[g0 * 4 + tid];
    __syncthreads();

    {   // layer 1: K=4, VALU. 2 consecutive features x 16 edges per thread.
        int j0 = (tid & 63) * 2, e0 = (tid >> 6) * 16;
        float w00 = We0[j0],       w01 = We0[j0 + 1];
        float w10 = We0[128 + j0], w11 = We0[128 + j0 + 1];
        float w20 = We0[256 + j0], w21 = We0[256 + j0 + 1];
        float w30 = We0[384 + j0], w31 = We0[384 + j0 + 1];
        float b0 = be0[j0], b1 = be0[j0 + 1];
        #pragma unroll 4
        for (int e = e0; e < e0 + 16; ++e) {
            float x0 = su.e.xl[e][0], x1 = su.e.xl[e][1];
            float x2 = su.e.xl[e][2], x3 = su.e.xl[e][3];
            float v0 = b0 + x0 * w00 + x1 * w10 + x2 * w20 + x3 * w30;
            float v1 = b1 + x0 * w01 + x1 * w11 + x2 * w21 + x3 * w31;
            f16x2 p;
            p[0] = (f16)fmaxf(v0, 0.f);
            p[1] = (f16)fmaxf(v1, 0.f);
            *(f16x2*)&su.e.y1[e][j0] = p;
        }
    }

    int m = lane & 15, q = lane >> 4;

    {   // layer 2 (operand-swapped). R12: hoist all W1t frags (burst prefetch,
        // L2 latency paid once instead of per s-iter).
        f16x8 wfr[4][4];                           // [ct][s] = 64 VGPR
        #pragma unroll
        for (int ct = 0; ct < 4; ++ct) {
            int n = (wv * 4 + ct) * 16 + m;
            #pragma unroll
            for (int s = 0; s < 4; ++s)
                wfr[ct][s] = *(const f16x8*)(W1t + n * 128 + s * 32 + q * 8);
        }
        __syncthreads();                           // y1 ready
        f32x4 acc[4][4];
        #pragma unroll
        for (int ct = 0; ct < 4; ++ct)
            #pragma unroll
            for (int rt = 0; rt < 4; ++rt) acc[ct][rt] = (f32x4){0.f, 0.f, 0.f, 0.f};
        #pragma unroll
        for (int s = 0; s < 4; ++s) {
            int k0 = s * 32 + q * 8;
            f16x8 afr[4];
            #pragma unroll
            for (int rt = 0; rt < 4; ++rt)
                afr[rt] = *(const f16x8*)&su.e.y1[rt * 16 + m][k0];
            #pragma unroll
            for (int ct = 0; ct < 4; ++ct)
                #pragma unroll
                for (int rt = 0; rt < 4; ++rt)
                    acc[ct][rt] = MFMA16(wfr[ct][s], afr[rt], acc[ct][rt]);
        }
        __syncthreads();
        // D: col = e (lane m), rows = 4 consecutive n -> packed 8B stores
        #pragma unroll
        for (int ct = 0; ct < 4; ++ct) {
            int n0 = (wv * 4 + ct) * 16 + q * 4;
            f32x4 bb = *(const f32x4*)&be1[n0];
            #pragma unroll
            for (int rt = 0; rt < 4; ++rt) {
                int e = rt * 16 + m;
                f16x4 pk;
                #pragma unroll
                for (int r = 0; r < 4; ++r)
                    pk[r] = (f16)fmaxf(acc[ct][rt][r] + bb[r], 0.f);
                *(f16x4*)&su.e.y2[e][n0] = pk;
            }
        }
    }

    {   // layer 3 (operand-swapped; out-stage back into y1). Hoisted W2t frags.
        f16x8 wfr2[2][8];                          // [ct][s] = 64 VGPR
        #pragma unroll
        for (int ct = 0; ct < 2; ++ct) {
            int n = (wv * 2 + ct) * 16 + m;
            #pragma unroll
            for (int s = 0; s < 8; ++s)
                wfr2[ct][s] = *(const f16x8*)(W2t + n * 256 + s * 32 + q * 8);
        }
        __syncthreads();                           // y2 ready
        f32x4 acc[2][4];
        #pragma unroll
        for (int ct = 0; ct < 2; ++ct)
            #pragma unroll
            for (int rt = 0; rt < 4; ++rt) acc[ct][rt] = (f32x4){0.f, 0.f, 0.f, 0.f};
        #pragma unroll
        for (int s = 0; s < 8; ++s) {
            int k0 = s * 32 + q * 8;
            f16x8 afr[4];
            #pragma unroll
            for (int rt = 0; rt < 4; ++rt)
                afr[rt] = *(const f16x8*)&su.e.y2[rt * 16 + m][k0];
            #pragma unroll
            for (int ct = 0; ct < 2; ++ct)
                #pragma unroll
                for (int rt = 0; rt < 4; ++rt)
                    acc[ct][rt] = MFMA16(wfr2[ct][s], afr[rt], acc[ct][rt]);
        }
        __syncthreads();
        #pragma unroll
        for (int ct = 0; ct < 2; ++ct) {
            int n0 = (wv * 2 + ct) * 16 + q * 4;
            f32x4 bb = *(const f32x4*)&be2[n0];
            #pragma unroll
            for (int rt = 0; rt < 4; ++rt) {
                int e = rt * 16 + m;
                f16x4 pk;
                #pragma unroll
                for (int r = 0; r < 4; ++r)
                    pk[r] = (f16)fmaxf(acc[ct][rt][r] + bb[r], 0.f);
                *(f16x4*)&su.e.y1[e][n0] = pk;
            }
        }
    }
    __syncthreads();

    #pragma unroll
    for (int j = 0; j < 4; ++j) {
        int c = tid + j * 256;
        int e = c >> 4, pp = c & 15;
        *(uint4*)(f + (g0 + e) * 128 + pp * 8) = *(const uint4*)&su.e.y1[e][pp * 8];
    }
}

__device__ void pgemm_body(SmemU& su, int tid, int ob, int nt,
                           const f16* __restrict__ h16,
                           const f16* __restrict__ We3h,
                           f16* __restrict__ P2) {
    int lane = tid & 63, wv = tid >> 6;

    #pragma unroll
    for (int j = 0; j < 4; ++j) {
        int c = tid + j * 256;
        int row = c >> 3, pp = c & 7;
        *(uint4*)&su.pg.in.Al[row][pp * 8] =
            *(const uint4*)(h16 + (size_t)(nt * 128 + row) * 64 + pp * 8);
    }
    #pragma unroll
    for (int j = 0; j < 4; ++j) {
        int c = tid + j * 256;
        int k = c >> 3, pp = c & 7;
        *(uint4*)&su.pg.in.Bl[k][pp * 8] =
            *(const uint4*)(We3h + ((size_t)(k * 64 + ob)) * 64 + pp * 8);
    }
    __syncthreads();

    int m = lane & 15, q = lane >> 4;
    f32x4 acc[2][8];
    #pragma unroll
    for (int ct = 0; ct < 2; ++ct)
        #pragma unroll
        for (int rt = 0; rt < 8; ++rt) acc[ct][rt] = (f32x4){0.f, 0.f, 0.f, 0.f};
    #pragma unroll
    for (int s = 0; s < 2; ++s) {
        int k0 = s * 32 + q * 8;
        f16x8 afr[8], bfr[2];
        #pragma unroll
        for (int rt = 0; rt < 8; ++rt)
            afr[rt] = *(const f16x8*)&su.pg.in.Al[rt * 16 + m][k0];
        #pragma unroll
        for (int ct = 0; ct < 2; ++ct)
            bfr[ct] = *(const f16x8*)&su.pg.in.Bl[(wv * 2 + ct) * 16 + m][k0];
        #pragma unroll
        for (int ct = 0; ct < 2; ++ct)
            #pragma unroll
            for (int rt = 0; rt < 8; ++rt)
                acc[ct][rt] = MFMA16(bfr[ct], afr[rt], acc[ct][rt]);
    }
    // All threads done READING Al/Bl before Ol (which aliases them) is written.
    __syncthreads();
    // D: col = v (lane m), rows = 4 consecutive c -> packed 8B stores
    #pragma unroll
    for (int ct = 0; ct < 2; ++ct) {
        int c0 = (wv * 2 + ct) * 16 + q * 4;
        #pragma unroll
        for (int rt = 0; rt < 8; ++rt) {
            int v = rt * 16 + m;
            f16x4 pk;
            #pragma unroll
            for (int r = 0; r < 4; ++r) pk[r] = (f16)acc[ct][rt][r];
            *(f16x4*)&su.pg.Ol[v][c0] = pk;
        }
    }
    __syncthreads();
    #pragma unroll
    for (int j = 0; j < 8; ++j) {
        int c = tid + j * 256;
        int row = c >> 4, pp = c & 15;
        *(uint4*)(P2 + ((size_t)(nt * 128 + row) * 64 + ob) * 128 + pp * 8) =
            *(const uint4*)&su.pg.Ol[row][pp * 8];
    }
}

// bias: biasb[b,o] = sum_i be3[o*64+i] * (sum_w h[b,w,i])
__device__ void bias_body(SmemU& su, int tid, int b,
                          const float* __restrict__ h,
                          const float* __restrict__ be3,
                          float* __restrict__ biasb) {
    int i = tid & 63, wq = tid >> 6;
    float s = 0.f;
    for (int w = wq; w < N; w += 4) s += h[((size_t)(b * N + w)) * H + i];
    su.bi.prt[wq][i] = s;
    __syncthreads();
    if (tid < 64)
        su.bi.hsum[tid] = su.bi.prt[0][tid] + su.bi.prt[1][tid]
                        + su.bi.prt[2][tid] + su.bi.prt[3][tid];
    __syncthreads();
    if (tid < 64) {
        float sb = 0.f;
        #pragma unroll 4
        for (int ii = 0; ii < H; ++ii) sb += be3[tid * H + ii] * su.bi.hsum[ii];
        biasb[b * 64 + tid] = sb;
    }
}

// -------------------------------------------------------------------------
// mega0: edge tiles (0..4095) + L0 p_gemm (4096..5119) + L0 bias (5120..5135)
__global__ __launch_bounds__(256, 3) void mega0_kernel(
    const float* __restrict__ am,
    const float* __restrict__ We0, const float* __restrict__ be0,
    const float* __restrict__ be1, const float* __restrict__ be2,
    const float* __restrict__ be3,
    const f16* __restrict__ wp,
    const float* __restrict__ h, const f16* __restrict__ h16,
    f16* __restrict__ f, f16* __restrict__ P2, float* __restrict__ biasb) {
    __shared__ SmemU su;
    int tid = threadIdx.x;
    int bid = blockIdx.x;
    if (bid < 4096) {
        edge_body(su, tid, bid, am, We0, be0, wp + OFF_W1T, be1, wp + OFF_W2T,
                  be2, f);
    } else if (bid < 5120) {
        int t = bid - 4096;
        pgemm_body(su, tid, t & 63, t >> 6, h16, wp + OFF_WE3H, P2);
    } else {
        bias_body(su, tid, bid - 5120, h, be3, biasb);
    }
}

// pg_bias: p_gemm (0..1023) + bias (1024..1039), for layers 1,2
__global__ __launch_bounds__(256, 3) void pg_bias_kernel(
    const float* __restrict__ be3, const f16* __restrict__ wp,
    const float* __restrict__ h, const f16* __restrict__ h16,
    f16* __restrict__ P2, float* __restrict__ biasb) {
    __shared__ SmemU su;
    int tid = threadIdx.x;
    int bid = blockIdx.x;
    if (bid < 1024) {
        pgemm_body(su, tid, bid & 63, bid >> 6, h16, wp + OFF_WE3H, P2);
    } else {
        bias_body(su, tid, bid - 1024, h, be3, biasb);
    }
}

// -------------------------------------------------------------------------
// msg GEMM: part[ws][(b,v),o] = sum_{w in split} sum_k f[(b,v),w,k]*P2[(b,w),o,k]
// part stored f16 (pure streaming, no reuse). R12: allow 3 blocks/CU.
__global__ __launch_bounds__(256, 3) void msg_mfma(
    const f16* __restrict__ f, const f16* __restrict__ P2,
    f16* __restrict__ part) {
    __shared__ f16 Al[128][136];
    __shared__ f16 Bl[64][136];
    int tid = threadIdx.x, lane = tid & 63, wv = tid >> 6;
    int ws = blockIdx.x;
    int b  = blockIdx.y;
    int m = lane & 15, q = lane >> 4;

    f32x4 acc[2][4];
    #pragma unroll
    for (int rt = 0; rt < 2; ++rt)
        #pragma unroll
        for (int ct = 0; ct < 4; ++ct) acc[rt][ct] = (f32x4){0.f, 0.f, 0.f, 0.f};

    for (int wi = 0; wi < 4; ++wi) {
        int w = ws * 4 + wi;
        #pragma unroll
        for (int j = 0; j < 8; ++j) {
            int c = tid + j * 256;
            int v = c >> 4, pp = c & 15;
            *(uint4*)&Al[v][pp * 8] =
                *(const uint4*)(f + (((size_t)(b * 128 + v) * 128 + w) * 128) + pp * 8);
        }
        #pragma unroll
        for (int j = 0; j < 4; ++j) {
            int c = tid + j * 256;
            int o = c >> 4, pp = c & 15;
            *(uint4*)&Bl[o][pp * 8] =
                *(const uint4*)(P2 + (((size_t)(b * 128 + w) * 64 + o) * 128) + pp * 8);
        }
        __syncthreads();
        #pragma unroll
        for (int s = 0; s < 4; ++s) {
            int k0 = s * 32 + q * 8;
            f16x8 afr[2], bfr[4];
            #pragma unroll
            for (int rt = 0; rt < 2; ++rt)
                afr[rt] = *(const f16x8*)&Al[(wv * 2 + rt) * 16 + m][k0];
            #pragma unroll
            for (int ct = 0; ct < 4; ++ct)
                bfr[ct] = *(const f16x8*)&Bl[ct * 16 + m][k0];
            #pragma unroll
            for (int rt = 0; rt < 2; ++rt)
                #pragma unroll
                for (int ct = 0; ct < 4; ++ct)
                    acc[rt][ct] = MFMA16(afr[rt], bfr[ct], acc[rt][ct]);
        }
        __syncthreads();
    }
    f16* pp = part + (size_t)ws * (2048 * 64);
    #pragma unroll
    for (int rt = 0; rt < 2; ++rt)
        #pragma unroll
        for (int ct = 0; ct < 4; ++ct) {
            int o = ct * 16 + m;
            #pragma unroll
            for (int r = 0; r < 4; ++r) {
                int v = (wv * 2 + rt) * 16 + q * 4 + r;
                pp[(size_t)(b * 128 + v) * 64 + o] = (f16)acc[rt][ct][r];
            }
        }
}

// -------------------------------------------------------------------------
// GRU: msg = biasb[b] + sum of 32 partials (f16); torch GRU step; mask.
__global__ __launch_bounds__(192) void gru_kernel(
    const float* __restrict__ biasb, const f16* __restrict__ part,
    float* __restrict__ h, f16* __restrict__ h16,
    const float* __restrict__ Wih, const float* __restrict__ Whh,
    const float* __restrict__ bih, const float* __restrict__ bhh,
    const int* __restrict__ g_size) {
    __shared__ float m_lds[M];
    __shared__ float h_lds[H];
    __shared__ float gi[3 * H], gh[3 * H];
    int tid = threadIdx.x;
    int bv  = blockIdx.x;
    int b = bv >> 7, v = bv & 127;

    if (tid < M) {
        float s = biasb[b * 64 + tid];
        #pragma unroll 8
        for (int sp = 0; sp < 32; ++sp)
            s += (float)part[(size_t)sp * (2048 * 64) + bv * 64 + tid];
        m_lds[tid] = s;
    } else if (tid < M + H) {
        h_lds[tid - M] = h[bv * H + (tid - M)];
    }
    __syncthreads();

    {
        float si = bih[tid], sh = bhh[tid];
        const float* wi = Wih + tid * M;
        const float* wh = Whh + tid * H;
        #pragma unroll 4
        for (int k = 0; k < M; ++k) si += wi[k] * m_lds[k];
        #pragma unroll 4
        for (int k = 0; k < H; ++k) sh += wh[k] * h_lds[k];
        gi[tid] = si;
        gh[tid] = sh;
    }
    __syncthreads();
    if (tid < H) {
        float r = 1.f / (1.f + expf(-(gi[tid] + gh[tid])));
        float z = 1.f / (1.f + expf(-(gi[H + tid] + gh[H + tid])));
        float n = tanhf(gi[2 * H + tid] + r * gh[2 * H + tid]);
        float hv = (1.f - z) * n + z * h_lds[tid];
        float maskf = (v < g_size[b]) ? 1.f : 0.f;
        hv *= maskf;
        h[bv * H + tid] = hv;
        h16[bv * H + tid] = (f16)hv;
    }
}

// -------------------------------------------------------------------------
// Readout via MFMA. 16-row blocks (128 blocks).
__global__ __launch_bounds__(256, 4) void readout_mfma(
    const f16* __restrict__ h16, const f16* __restrict__ hin16,
    const int* __restrict__ g_size, const f16* __restrict__ wp,
    const float* __restrict__ bi0, const float* __restrict__ bi1,
    const float* __restrict__ bi2, const float* __restrict__ bi3,
    const float* __restrict__ bj0, const float* __restrict__ bj1,
    const float* __restrict__ bj2, const float* __restrict__ bj3,
    float* __restrict__ contrib) {
    __shared__ f16 Xl[16][104];
    __shared__ f16 A1[16][136];
    __shared__ f16 A2[16][264];
    __shared__ float Gl[16][36];
    const f16* Ri0 = wp + OFF_RI0; const f16* Ri1 = wp + OFF_RI1;
    const f16* Ri2 = wp + OFF_RI2; const f16* Ri3 = wp + OFF_RI3;
    const f16* Rj0 = wp + OFF_RJ0; const f16* Rj1 = wp + OFF_RJ1;
    const f16* Rj2 = wp + OFF_RJ2; const f16* Rj3 = wp + OFF_RJ3;
    int tid = threadIdx.x, lane = tid & 63, wv = tid >> 6;
    int m = lane & 15, q = lane >> 4;
    int r0 = blockIdx.x * 16;

    {
        if (tid < 128) {
            int row = tid >> 3, pp = tid & 7;
            *(uint4*)&Xl[row][pp * 8] =
                *(const uint4*)(h16 + (size_t)(r0 + row) * 64 + pp * 8);
        }
        if (tid < 64) {
            int row2 = tid >> 2, p2 = tid & 3;
            *(uint4*)&Xl[row2][64 + p2 * 8] =
                *(const uint4*)(hin16 + (size_t)(r0 + row2) * 32 + p2 * 8);
        }
    }
    __syncthreads();

    // i-chain L0
    {
        f32x4 acc[2];
        acc[0] = (f32x4){0.f, 0.f, 0.f, 0.f};
        acc[1] = (f32x4){0.f, 0.f, 0.f, 0.f};
        #pragma unroll
        for (int s = 0; s < 3; ++s) {
            int k0 = s * 32 + q * 8;
            f16x8 afr = *(const f16x8*)&Xl[m][k0];
            #pragma unroll
            for (int ct = 0; ct < 2; ++ct) {
                f16x8 bfr = *(const f16x8*)(Ri0 + ((wv * 2 + ct) * 16 + m) * 96 + k0);
                acc[ct] = MFMA16(afr, bfr, acc[ct]);
            }
        }
        #pragma unroll
        for (int ct = 0; ct < 2; ++ct) {
            int n = (wv * 2 + ct) * 16 + m;
            float bb = bi0[n];
            #pragma unroll
            for (int r = 0; r < 4; ++r)
                A1[q * 4 + r][n] = (f16)fmaxf(acc[ct][r] + bb, 0.f);
        }
    }
    __syncthreads();

    // i-chain L1
    {
        f32x4 acc[4];
        #pragma unroll
        for (int ct = 0; ct < 4; ++ct) acc[ct] = (f32x4){0.f, 0.f, 0.f, 0.f};
        #pragma unroll
        for (int s = 0; s < 4; ++s) {
            int k0 = s * 32 + q * 8;
            f16x8 afr = *(const f16x8*)&A1[m][k0];
            #pragma unroll
            for (int ct = 0; ct < 4; ++ct) {
                f16x8 bfr = *(const f16x8*)(Ri1 + ((wv * 4 + ct) * 16 + m) * 128 + k0);
                acc[ct] = MFMA16(afr, bfr, acc[ct]);
            }
        }
        #pragma unroll
        for (int ct = 0; ct < 4; ++ct) {
            int n = (wv * 4 + ct) * 16 + m;
            float bb = bi1[n];
            #pragma unroll
            for (int r = 0; r < 4; ++r)
                A2[q * 4 + r][n] = (f16)fmaxf(acc[ct][r] + bb, 0.f);
        }
    }
    __syncthreads();

    // i-chain L2
    {
        f32x4 acc[2];
        acc[0] = (f32x4){0.f, 0.f, 0.f, 0.f};
        acc[1] = (f32x4){0.f, 0.f, 0.f, 0.f};
        #pragma unroll
        for (int s = 0; s < 8; ++s) {
            int k0 = s * 32 + q * 8;
            f16x8 afr = *(const f16x8*)&A2[m][k0];
            #pragma unroll
            for (int ct = 0; ct < 2; ++ct) {
                f16x8 bfr = *(const f16x8*)(Ri2 + ((wv * 2 + ct) * 16 + m) * 256 + k0);
                acc[ct] = MFMA16(afr, bfr, acc[ct]);
            }
        }
        __syncthreads();
        #pragma unroll
        for (int ct = 0; ct < 2; ++ct) {
            int n = (wv * 2 + ct) * 16 + m;
            float bb = bi2[n];
            #pragma unroll
            for (int r = 0; r < 4; ++r)
                A1[q * 4 + r][n] = (f16)fmaxf(acc[ct][r] + bb, 0.f);
        }
    }
    __syncthreads();

    // i-chain L3 -> gate
    if (wv < 2) {
        f32x4 acc = (f32x4){0.f, 0.f, 0.f, 0.f};
        int n = wv * 16 + m;
        #pragma unroll
        for (int s = 0; s < 4; ++s) {
            int k0 = s * 32 + q * 8;
            f16x8 bfr = *(const f16x8*)(Ri3 + n * 128 + k0);
            f16x8 afr = *(const f16x8*)&A1[m][k0];
            acc = MFMA16(afr, bfr, acc);
        }
        float bb = bi3[n];
        #pragma unroll
        for (int r = 0; r < 4; ++r)
            Gl[q * 4 + r][n] = 1.f / (1.f + expf(-(acc[r] + bb)));
    }
    __syncthreads();

    // j-chain L0
    {
        f32x4 acc[2];
        acc[0] = (f32x4){0.f, 0.f, 0.f, 0.f};
        acc[1] = (f32x4){0.f, 0.f, 0.f, 0.f};
        #pragma unroll
        for (int s = 0; s < 2; ++s) {
            int k0 = s * 32 + q * 8;
            f16x8 afr = *(const f16x8*)&Xl[m][k0];
            #pragma unroll
            for (int ct = 0; ct < 2; ++ct) {
                f16x8 bfr = *(const f16x8*)(Rj0 + ((wv * 2 + ct) * 16 + m) * 64 + k0);
                acc[ct] = MFMA16(afr, bfr, acc[ct]);
            }
        }
        __syncthreads();
        #pragma unroll
        for (int ct = 0; ct < 2; ++ct) {
            int n = (wv * 2 + ct) * 16 + m;
            float bb = bj0[n];
            #pragma unroll
            for (int r = 0; r < 4; ++r)
                A1[q * 4 + r][n] = (f16)fmaxf(acc[ct][r] + bb, 0.f);
        }
    }
    __syncthreads();

    // j-chain L1
    {
        f32x4 acc[4];
        #pragma unroll
        for (int ct = 0; ct < 4; ++ct) acc[ct] = (f32x4){0.f, 0.f, 0.f, 0.f};
        #pragma unroll
        for (int s = 0; s < 4; ++s) {
            int k0 = s * 32 + q * 8;
            f16x8 afr = *(const f16x8*)&A1[m][k0];
            #pragma unroll
            for (int ct = 0; ct < 4; ++ct) {
                f16x8 bfr = *(const f16x8*)(Rj1 + ((wv * 4 + ct) * 16 + m) * 128 + k0);
                acc[ct] = MFMA16(afr, bfr, acc[ct]);
            }
        }
        #pragma unroll
        for (int ct = 0; ct < 4; ++ct) {
            int n = (wv * 4 + ct) * 16 + m;
            float bb = bj1[n];
            #pragma unroll
            for (int r = 0; r < 4; ++r)
                A2[q * 4 + r][n] = (f16)fmaxf(acc[ct][r] + bb, 0.f);
        }
    }
    __syncthreads();

    // j-chain L2
    {
        f32x4 acc[2];
        acc[0] = (f32x4){0.f, 0.f, 0.f, 0.f};
        acc[1] = (f32x4){0.f, 0.f, 0.f, 0.f};
        #pragma unroll
        for (int s = 0; s < 8; ++s) {
            int k0 = s * 32 + q * 8;
            f16x8 afr = *(const f16x8*)&A2[m][k0];
            #pragma unroll
            for (int ct = 0; ct < 2; ++ct) {
                f16x8 bfr = *(const f16x8*)(Rj2 + ((wv * 2 + ct) * 16 + m) * 256 + k0);
                acc[ct] = MFMA16(afr, bfr, acc[ct]);
            }
        }
        __syncthreads();
        #pragma unroll
        for (int ct = 0; ct < 2; ++ct) {
            int n = (wv * 2 + ct) * 16 + m;
            float bb = bj2[n];
            #pragma unroll
            for (int r = 0; r < 4; ++r)
                A1[q * 4 + r][n] = (f16)fmaxf(acc[ct][r] + bb, 0.f);
        }
    }
    __syncthreads();

    // j-chain L3 + combine
    if (wv < 2) {
        f32x4 acc = (f32x4){0.f, 0.f, 0.f, 0.f};
        int n = wv * 16 + m;
        #pragma unroll
        for (int s = 0; s < 4; ++s) {
            int k0 = s * 32 + q * 8;
            f16x8 bfr = *(const f16x8*)(Rj3 + n * 128 + k0);
            f16x8 afr = *(const f16x8*)&A1[m][k0];
            acc = MFMA16(afr, bfr, acc);
        }
        float bb = bj3[n];
        #pragma unroll
        for (int r = 0; r < 4; ++r) {
            int row = q * 4 + r;
            int rg = r0 + row;
            int b = rg >> 7, v = rg & 127;
            float maskf = (v < g_size[b]) ? 1.f : 0.f;
            contrib[(size_t)rg * T + n] = maskf * Gl[row][n] * (acc[r] + bb);
        }
    }
}

// -------------------------------------------------------------------------
__global__ __launch_bounds__(64) void finalize_kernel(const float* __restrict__ contrib,
                                                      float* __restrict__ out) {
    __shared__ float res[T];
    int b = blockIdx.x;
    int o = threadIdx.x;
    if (o < T) {
        float s = 0.f;
        for (int v = 0; v < N; ++v) s += contrib[(b * N + v) * T + o];
        res[o] = s;
    }
    __syncthreads();
    if (o < T) {
        float mx = res[0];
        for (int i = 1; i < T; ++i) mx = fmaxf(mx, res[i]);
        float se = 0.f;
        for (int i = 0; i < T; ++i) se += expf(res[i] - mx);
        out[b * T + o] = res[o] - mx - logf(se);
    }
}

// -------------------------------------------------------------------------
extern "C" void kernel_launch(void* const* d_in, const int* in_sizes, int n_in,
                              void* d_out, int out_size, void* d_ws, size_t ws_size,
                              hipStream_t stream) {
    (void)in_sizes; (void)n_in; (void)out_size; (void)ws_size;
    const float* h_in = (const float*)d_in[0];
    const float* am   = (const float*)d_in[1];
    const int*   g_sz = (const int*)d_in[2];
    const float* We0 = (const float*)d_in[3],  *be0 = (const float*)d_in[4];
    const float* We1 = (const float*)d_in[5],  *be1 = (const float*)d_in[6];
    const float* We2 = (const float*)d_in[7],  *be2 = (const float*)d_in[8];
    const float* We3 = (const float*)d_in[9],  *be3 = (const float*)d_in[10];
    const float* Wih = (const float*)d_in[11], *Whh = (const float*)d_in[12];
    const float* bih = (const float*)d_in[13], *bhh = (const float*)d_in[14];
    const float* Wi0 = (const float*)d_in[15], *bi0 = (const float*)d_in[16];
    const float* Wj0 = (const float*)d_in[17], *bj0 = (const float*)d_in[18];
    const float* Wi1 = (const float*)d_in[19], *bi1 = (const float*)d_in[20];
    const float* Wj1 = (const float*)d_in[21], *bj1 = (const float*)d_in[22];
    const float* Wi2 = (const float*)d_in[23], *bi2 = (const float*)d_in[24];
    const float* Wj2 = (const float*)d_in[25], *bj2 = (const float*)d_in[26];
    const float* Wi3 = (const float*)d_in[27], *bi3 = (const float*)d_in[28];
    const float* Wj3 = (const float*)d_in[29], *bj3 = (const float*)d_in[30];

    float* out = (float*)d_out;

    // workspace layout (~110 MB); part f16
    f16*   f    = (f16*)d_ws;                             // 33554432 halves
    f16*   P2   = f + (size_t)33554432;                   // 16777216 halves
    f16*   part = P2 + (size_t)16777216;                  // 4194304 halves
    float* h    = (float*)(part + (size_t)4194304);       // 131072
    float* biasb = h + 131072;                            // 1024
    float* contrib = biasb + 1024;                        // 65536
    f16*   h16  = (f16*)(contrib + 65536);                // 131072 halves
    f16*   hin16 = h16 + 131072;                          // 65536 halves
    f16*   wp   = hin16 + 65536;                          // 749568 halves

    prep_kernel<<<(WPACK_SZ + 255) / 256, 256, 0, stream>>>(
        h_in, We1, We2, We3, Wi0, Wi1, Wi2, Wi3, Wj0, Wj1, Wj2, Wj3,
        h, h16, hin16, wp);

    // layer 0: edge + p_gemm + bias fused into one launch
    mega0_kernel<<<4096 + 1024 + 16, 256, 0, stream>>>(
        am, We0, be0, be1, be2, be3, wp, h, h16, f, P2, biasb);
    msg_mfma<<<dim3(32, 16), 256, 0, stream>>>(f, P2, part);
    gru_kernel<<<B * N, 192, 0, stream>>>(biasb, part, h, h16,
                                          Wih, Whh, bih, bhh, g_sz);

    for (int l = 1; l < 3; ++l) {
        pg_bias_kernel<<<1024 + 16, 256, 0, stream>>>(be3, wp, h, h16, P2, biasb);
        msg_mfma<<<dim3(32, 16), 256, 0, stream>>>(f, P2, part);
        gru_kernel<<<B * N, 192, 0, stream>>>(biasb, part, h, h16,
                                              Wih, Whh, bih, bhh, g_sz);
    }

    readout_mfma<<<128, 256, 0, stream>>>(h16, hin16, g_sz, wp,
                                          bi0, bi1, bi2, bi3,
                                          bj0, bj1, bj2, bj3, contrib);
    finalize_kernel<<<B, 64, 0, stream>>>(contrib, out);
}

// Round 7
// 391.350 us; speedup vs baseline: 1.0027x; 1.0027x over previous
//
#include <hip/hip_runtime.h>
#include <math.h>

// Problem constants
#define B   16
#define N   128
#define E   4
#define H   64
#define M   64
#define IN_ 32
#define T   32
#define K1  128
#define K2  256
#define K3  128

typedef _Float16 f16;
typedef f16  f16x8 __attribute__((ext_vector_type(8)));
typedef f16  f16x4 __attribute__((ext_vector_type(4)));
typedef f16  f16x2 __attribute__((ext_vector_type(2)));
typedef float f32x4 __attribute__((ext_vector_type(4)));

#define MFMA16(a, b, c) __builtin_amdgcn_mfma_f32_16x16x32_f16(a, b, c, 0, 0, 0)

// fp16 weight pack offsets (halves)
#define OFF_W1T   0
#define OFF_W2T   32768
#define OFF_WE3H  65536
#define OFF_RI0   589824
#define OFF_RI1   602112
#define OFF_RI2   634880
#define OFF_RI3   667648
#define OFF_RJ0   671744
#define OFF_RJ1   679936
#define OFF_RJ2   712704
#define OFF_RJ3   745472
#define WPACK_SZ  749568

// R13: R12's weight-hoist refuted (compiler re-sank loads, VGPR 84 not ~150;
// mega0 98->105). Edge body reverted to R11 exactly (best, 387.7us).
// Kept from R12: msg_mfma (256,3). NEW: part relayout [bv][sp][o] -- gru's 32
// partial reads per (bv,o) were strided 8MB apart (32 scattered lines/thread);
// now one contiguous 4KB block per gru workgroup. msg write coalescing
// unchanged (16-consecutive-o segments either way).
union SmemU {
    struct { float xl[64][4]; f16 y1[64][136]; f16 y2[64][264]; } e;   // 52224
    union {
        struct { f16 Al[128][72]; f16 Bl[128][72]; } in;               // 36864
        f16 Ol[128][136];                                              // 34816
    } pg;
    struct { float prt[4][64]; float hsum[64]; float bias[64]; } bi;   // 1536
};

// -------------------------------------------------------------------------
// prep: pad h (fp32/fp16 + hin16) AND build fp16 weight pack. One launch.
__global__ __launch_bounds__(256) void prep_kernel(
    const float* __restrict__ h_in,
    const float* __restrict__ We1, const float* __restrict__ We2,
    const float* __restrict__ We3,
    const float* __restrict__ Wi0, const float* __restrict__ Wi1,
    const float* __restrict__ Wi2, const float* __restrict__ Wi3,
    const float* __restrict__ Wj0, const float* __restrict__ Wj1,
    const float* __restrict__ Wj2, const float* __restrict__ Wj3,
    float* __restrict__ h, f16* __restrict__ h16, f16* __restrict__ hin16,
    f16* __restrict__ wp) {
    int idx = blockIdx.x * 256 + threadIdx.x;
    if (idx < B * N * H) {
        int i  = idx & (H - 1);
        int bn = idx >> 6;
        float v = (i < IN_) ? h_in[bn * IN_ + i] : 0.f;
        h[idx] = v;
        h16[idx] = (f16)v;
        if (i < IN_) hin16[bn * IN_ + i] = (f16)v;
    }
    if (idx >= WPACK_SZ) return;
    if (idx < OFF_W2T) {                          // W1t [256][128]
        int j = idx >> 7, k = idx & 127;
        wp[idx] = (f16)We1[k * 256 + j];
    } else if (idx < OFF_WE3H) {                  // W2t [128][256]
        int t = idx - OFF_W2T;
        int j = t >> 8, k = t & 255;
        wp[idx] = (f16)We2[k * 128 + j];
    } else if (idx < OFF_RI0) {                   // We3h copy
        wp[idx] = (f16)We3[idx - OFF_WE3H];
    } else if (idx < OFF_RI1) {                   // Ri0 [128][96]
        int t = idx - OFF_RI0;
        int n = t / 96, c = t % 96;
        wp[idx] = (f16)Wi0[c * 128 + n];
    } else if (idx < OFF_RI2) {                   // Ri1 [256][128]
        int t = idx - OFF_RI1;
        int n = t >> 7, k = t & 127;
        wp[idx] = (f16)Wi1[k * 256 + n];
    } else if (idx < OFF_RI3) {                   // Ri2 [128][256]
        int t = idx - OFF_RI2;
        int n = t >> 8, k = t & 255;
        wp[idx] = (f16)Wi2[k * 128 + n];
    } else if (idx < OFF_RJ0) {                   // Ri3 [32][128]
        int t = idx - OFF_RI3;
        int n = t >> 7, k = t & 127;
        wp[idx] = (f16)Wi3[k * 32 + n];
    } else if (idx < OFF_RJ1) {                   // Rj0 [128][64]
        int t = idx - OFF_RJ0;
        int n = t >> 6, c = t & 63;
        wp[idx] = (f16)Wj0[c * 128 + n];
    } else if (idx < OFF_RJ2) {                   // Rj1 [256][128]
        int t = idx - OFF_RJ1;
        int n = t >> 7, k = t & 127;
        wp[idx] = (f16)Wj1[k * 256 + n];
    } else if (idx < OFF_RJ3) {                   // Rj2 [128][256]
        int t = idx - OFF_RJ2;
        int n = t >> 8, k = t & 255;
        wp[idx] = (f16)Wj2[k * 128 + n];
    } else {                                      // Rj3 [32][128]
        int t = idx - OFF_RJ3;
        int n = t >> 7, k = t & 127;
        wp[idx] = (f16)Wj3[k * 32 + n];
    }
}

// ===================== task bodies (R11-proven, 256 threads) ================

__device__ void edge_body(SmemU& su, int tid, int tile,
                          const float* __restrict__ am,
                          const float* __restrict__ We0,
                          const float* __restrict__ be0,
                          const f16* __restrict__ W1t,
                          const float* __restrict__ be1,
                          const f16* __restrict__ W2t,
                          const float* __restrict__ be2,
                          f16* __restrict__ f) {
    int lane = tid & 63, wv = tid >> 6;
    long long g0 = (long long)tile * 64;

    ((float*)su.e.xl)[tid] = am[g0 * 4 + tid];
    __syncthreads();

    {   // layer 1: K=4, VALU. 2 consecutive features x 16 edges per thread;
        // packed dword writes (lane-linear banks).
        int j0 = (tid & 63) * 2, e0 = (tid >> 6) * 16;
        float w00 = We0[j0],       w01 = We0[j0 + 1];
        float w10 = We0[128 + j0], w11 = We0[128 + j0 + 1];
        float w20 = We0[256 + j0], w21 = We0[256 + j0 + 1];
        float w30 = We0[384 + j0], w31 = We0[384 + j0 + 1];
        float b0 = be0[j0], b1 = be0[j0 + 1];
        #pragma unroll 4
        for (int e = e0; e < e0 + 16; ++e) {
            float x0 = su.e.xl[e][0], x1 = su.e.xl[e][1];
            float x2 = su.e.xl[e][2], x3 = su.e.xl[e][3];
            float v0 = b0 + x0 * w00 + x1 * w10 + x2 * w20 + x3 * w30;
            float v1 = b1 + x0 * w01 + x1 * w11 + x2 * w21 + x3 * w31;
            f16x2 p;
            p[0] = (f16)fmaxf(v0, 0.f);
            p[1] = (f16)fmaxf(v1, 0.f);
            *(f16x2*)&su.e.y1[e][j0] = p;
        }
    }
    __syncthreads();

    int m = lane & 15, q = lane >> 4;

    {   // layer 2 (operand-swapped: A=weights, B=activations)
        f32x4 acc[4][4];
        #pragma unroll
        for (int ct = 0; ct < 4; ++ct)
            #pragma unroll
            for (int rt = 0; rt < 4; ++rt) acc[ct][rt] = (f32x4){0.f, 0.f, 0.f, 0.f};
        #pragma unroll
        for (int s = 0; s < 4; ++s) {
            int k0 = s * 32 + q * 8;
            f16x8 afr[4], bfr[4];
            #pragma unroll
            for (int rt = 0; rt < 4; ++rt)
                afr[rt] = *(const f16x8*)&su.e.y1[rt * 16 + m][k0];
            #pragma unroll
            for (int ct = 0; ct < 4; ++ct) {
                int n = (wv * 4 + ct) * 16 + m;
                bfr[ct] = *(const f16x8*)(W1t + n * 128 + k0);
            }
            #pragma unroll
            for (int ct = 0; ct < 4; ++ct)
                #pragma unroll
                for (int rt = 0; rt < 4; ++rt)
                    acc[ct][rt] = MFMA16(bfr[ct], afr[rt], acc[ct][rt]);
        }
        // D: col = e (lane m), rows = 4 consecutive n -> packed 8B stores
        #pragma unroll
        for (int ct = 0; ct < 4; ++ct) {
            int n0 = (wv * 4 + ct) * 16 + q * 4;
            f32x4 bb = *(const f32x4*)&be1[n0];
            #pragma unroll
            for (int rt = 0; rt < 4; ++rt) {
                int e = rt * 16 + m;
                f16x4 pk;
                #pragma unroll
                for (int r = 0; r < 4; ++r)
                    pk[r] = (f16)fmaxf(acc[ct][rt][r] + bb[r], 0.f);
                *(f16x4*)&su.e.y2[e][n0] = pk;
            }
        }
    }
    __syncthreads();

    {   // layer 3 (operand-swapped; out-stage back into y1)
        f32x4 acc[2][4];
        #pragma unroll
        for (int ct = 0; ct < 2; ++ct)
            #pragma unroll
            for (int rt = 0; rt < 4; ++rt) acc[ct][rt] = (f32x4){0.f, 0.f, 0.f, 0.f};
        #pragma unroll
        for (int s = 0; s < 8; ++s) {
            int k0 = s * 32 + q * 8;
            f16x8 afr[4], bfr[2];
            #pragma unroll
            for (int rt = 0; rt < 4; ++rt)
                afr[rt] = *(const f16x8*)&su.e.y2[rt * 16 + m][k0];
            #pragma unroll
            for (int ct = 0; ct < 2; ++ct) {
                int n = (wv * 2 + ct) * 16 + m;
                bfr[ct] = *(const f16x8*)(W2t + n * 256 + k0);
            }
            #pragma unroll
            for (int ct = 0; ct < 2; ++ct)
                #pragma unroll
                for (int rt = 0; rt < 4; ++rt)
                    acc[ct][rt] = MFMA16(bfr[ct], afr[rt], acc[ct][rt]);
        }
        #pragma unroll
        for (int ct = 0; ct < 2; ++ct) {
            int n0 = (wv * 2 + ct) * 16 + q * 4;
            f32x4 bb = *(const f32x4*)&be2[n0];
            #pragma unroll
            for (int rt = 0; rt < 4; ++rt) {
                int e = rt * 16 + m;
                f16x4 pk;
                #pragma unroll
                for (int r = 0; r < 4; ++r)
                    pk[r] = (f16)fmaxf(acc[ct][rt][r] + bb[r], 0.f);
                *(f16x4*)&su.e.y1[e][n0] = pk;
            }
        }
    }
    __syncthreads();

    #pragma unroll
    for (int j = 0; j < 4; ++j) {
        int c = tid + j * 256;
        int e = c >> 4, pp = c & 15;
        *(uint4*)(f + (g0 + e) * 128 + pp * 8) = *(const uint4*)&su.e.y1[e][pp * 8];
    }
}

__device__ void pgemm_body(SmemU& su, int tid, int ob, int nt,
                           const f16* __restrict__ h16,
                           const f16* __restrict__ We3h,
                           f16* __restrict__ P2) {
    int lane = tid & 63, wv = tid >> 6;

    #pragma unroll
    for (int j = 0; j < 4; ++j) {
        int c = tid + j * 256;
        int row = c >> 3, pp = c & 7;
        *(uint4*)&su.pg.in.Al[row][pp * 8] =
            *(const uint4*)(h16 + (size_t)(nt * 128 + row) * 64 + pp * 8);
    }
    #pragma unroll
    for (int j = 0; j < 4; ++j) {
        int c = tid + j * 256;
        int k = c >> 3, pp = c & 7;
        *(uint4*)&su.pg.in.Bl[k][pp * 8] =
            *(const uint4*)(We3h + ((size_t)(k * 64 + ob)) * 64 + pp * 8);
    }
    __syncthreads();

    int m = lane & 15, q = lane >> 4;
    f32x4 acc[2][8];
    #pragma unroll
    for (int ct = 0; ct < 2; ++ct)
        #pragma unroll
        for (int rt = 0; rt < 8; ++rt) acc[ct][rt] = (f32x4){0.f, 0.f, 0.f, 0.f};
    #pragma unroll
    for (int s = 0; s < 2; ++s) {
        int k0 = s * 32 + q * 8;
        f16x8 afr[8], bfr[2];
        #pragma unroll
        for (int rt = 0; rt < 8; ++rt)
            afr[rt] = *(const f16x8*)&su.pg.in.Al[rt * 16 + m][k0];
        #pragma unroll
        for (int ct = 0; ct < 2; ++ct)
            bfr[ct] = *(const f16x8*)&su.pg.in.Bl[(wv * 2 + ct) * 16 + m][k0];
        #pragma unroll
        for (int ct = 0; ct < 2; ++ct)
            #pragma unroll
            for (int rt = 0; rt < 8; ++rt)
                acc[ct][rt] = MFMA16(bfr[ct], afr[rt], acc[ct][rt]);
    }
    // All threads done READING Al/Bl before Ol (which aliases them) is written.
    __syncthreads();
    // D: col = v (lane m), rows = 4 consecutive c -> packed 8B stores
    #pragma unroll
    for (int ct = 0; ct < 2; ++ct) {
        int c0 = (wv * 2 + ct) * 16 + q * 4;
        #pragma unroll
        for (int rt = 0; rt < 8; ++rt) {
            int v = rt * 16 + m;
            f16x4 pk;
            #pragma unroll
            for (int r = 0; r < 4; ++r) pk[r] = (f16)acc[ct][rt][r];
            *(f16x4*)&su.pg.Ol[v][c0] = pk;
        }
    }
    __syncthreads();
    #pragma unroll
    for (int j = 0; j < 8; ++j) {
        int c = tid + j * 256;
        int row = c >> 4, pp = c & 15;
        *(uint4*)(P2 + ((size_t)(nt * 128 + row) * 64 + ob) * 128 + pp * 8) =
            *(const uint4*)&su.pg.Ol[row][pp * 8];
    }
}

// bias: biasb[b,o] = sum_i be3[o*64+i] * (sum_w h[b,w,i])
__device__ void bias_body(SmemU& su, int tid, int b,
                          const float* __restrict__ h,
                          const float* __restrict__ be3,
                          float* __restrict__ biasb) {
    int i = tid & 63, wq = tid >> 6;
    float s = 0.f;
    for (int w = wq; w < N; w += 4) s += h[((size_t)(b * N + w)) * H + i];
    su.bi.prt[wq][i] = s;
    __syncthreads();
    if (tid < 64)
        su.bi.hsum[tid] = su.bi.prt[0][tid] + su.bi.prt[1][tid]
                        + su.bi.prt[2][tid] + su.bi.prt[3][tid];
    __syncthreads();
    if (tid < 64) {
        float sb = 0.f;
        #pragma unroll 4
        for (int ii = 0; ii < H; ++ii) sb += be3[tid * H + ii] * su.bi.hsum[ii];
        biasb[b * 64 + tid] = sb;
    }
}

// -------------------------------------------------------------------------
// mega0: edge tiles (0..4095) + L0 p_gemm (4096..5119) + L0 bias (5120..5135)
__global__ __launch_bounds__(256, 3) void mega0_kernel(
    const float* __restrict__ am,
    const float* __restrict__ We0, const float* __restrict__ be0,
    const float* __restrict__ be1, const float* __restrict__ be2,
    const float* __restrict__ be3,
    const f16* __restrict__ wp,
    const float* __restrict__ h, const f16* __restrict__ h16,
    f16* __restrict__ f, f16* __restrict__ P2, float* __restrict__ biasb) {
    __shared__ SmemU su;
    int tid = threadIdx.x;
    int bid = blockIdx.x;
    if (bid < 4096) {
        edge_body(su, tid, bid, am, We0, be0, wp + OFF_W1T, be1, wp + OFF_W2T,
                  be2, f);
    } else if (bid < 5120) {
        int t = bid - 4096;
        pgemm_body(su, tid, t & 63, t >> 6, h16, wp + OFF_WE3H, P2);
    } else {
        bias_body(su, tid, bid - 5120, h, be3, biasb);
    }
}

// pg_bias: p_gemm (0..1023) + bias (1024..1039), for layers 1,2
__global__ __launch_bounds__(256, 3) void pg_bias_kernel(
    const float* __restrict__ be3, const f16* __restrict__ wp,
    const float* __restrict__ h, const f16* __restrict__ h16,
    f16* __restrict__ P2, float* __restrict__ biasb) {
    __shared__ SmemU su;
    int tid = threadIdx.x;
    int bid = blockIdx.x;
    if (bid < 1024) {
        pgemm_body(su, tid, bid & 63, bid >> 6, h16, wp + OFF_WE3H, P2);
    } else {
        bias_body(su, tid, bid - 1024, h, be3, biasb);
    }
}

// -------------------------------------------------------------------------
// msg GEMM: part[(b,v)][ws][o] = sum_{w in split} sum_k f[(b,v),w,k]*P2[(b,w),o,k]
// part stored f16. R13: [bv][sp][o] layout so gru reads one contiguous 4KB
// block per workgroup (was 32 reads strided 8MB apart).
__global__ __launch_bounds__(256, 3) void msg_mfma(
    const f16* __restrict__ f, const f16* __restrict__ P2,
    f16* __restrict__ part) {
    __shared__ f16 Al[128][136];
    __shared__ f16 Bl[64][136];
    int tid = threadIdx.x, lane = tid & 63, wv = tid >> 6;
    int ws = blockIdx.x;
    int b  = blockIdx.y;
    int m = lane & 15, q = lane >> 4;

    f32x4 acc[2][4];
    #pragma unroll
    for (int rt = 0; rt < 2; ++rt)
        #pragma unroll
        for (int ct = 0; ct < 4; ++ct) acc[rt][ct] = (f32x4){0.f, 0.f, 0.f, 0.f};

    for (int wi = 0; wi < 4; ++wi) {
        int w = ws * 4 + wi;
        #pragma unroll
        for (int j = 0; j < 8; ++j) {
            int c = tid + j * 256;
            int v = c >> 4, pp = c & 15;
            *(uint4*)&Al[v][pp * 8] =
                *(const uint4*)(f + (((size_t)(b * 128 + v) * 128 + w) * 128) + pp * 8);
        }
        #pragma unroll
        for (int j = 0; j < 4; ++j) {
            int c = tid + j * 256;
            int o = c >> 4, pp = c & 15;
            *(uint4*)&Bl[o][pp * 8] =
                *(const uint4*)(P2 + (((size_t)(b * 128 + w) * 64 + o) * 128) + pp * 8);
        }
        __syncthreads();
        #pragma unroll
        for (int s = 0; s < 4; ++s) {
            int k0 = s * 32 + q * 8;
            f16x8 afr[2], bfr[4];
            #pragma unroll
            for (int rt = 0; rt < 2; ++rt)
                afr[rt] = *(const f16x8*)&Al[(wv * 2 + rt) * 16 + m][k0];
            #pragma unroll
            for (int ct = 0; ct < 4; ++ct)
                bfr[ct] = *(const f16x8*)&Bl[ct * 16 + m][k0];
            #pragma unroll
            for (int rt = 0; rt < 2; ++rt)
                #pragma unroll
                for (int ct = 0; ct < 4; ++ct)
                    acc[rt][ct] = MFMA16(afr[rt], bfr[ct], acc[rt][ct]);
        }
        __syncthreads();
    }
    #pragma unroll
    for (int rt = 0; rt < 2; ++rt)
        #pragma unroll
        for (int ct = 0; ct < 4; ++ct) {
            int o = ct * 16 + m;
            #pragma unroll
            for (int r = 0; r < 4; ++r) {
                int v = (wv * 2 + rt) * 16 + q * 4 + r;
                part[((size_t)(b * 128 + v) * 32 + ws) * 64 + o] = (f16)acc[rt][ct][r];
            }
        }
}

// -------------------------------------------------------------------------
// GRU: msg = biasb[b] + sum of 32 partials (f16, contiguous [bv][sp][o]);
// torch GRU step; mask.
__global__ __launch_bounds__(192) void gru_kernel(
    const float* __restrict__ biasb, const f16* __restrict__ part,
    float* __restrict__ h, f16* __restrict__ h16,
    const float* __restrict__ Wih, const float* __restrict__ Whh,
    const float* __restrict__ bih, const float* __restrict__ bhh,
    const int* __restrict__ g_size) {
    __shared__ float m_lds[M];
    __shared__ float h_lds[H];
    __shared__ float gi[3 * H], gh[3 * H];
    int tid = threadIdx.x;
    int bv  = blockIdx.x;
    int b = bv >> 7, v = bv & 127;

    if (tid < M) {
        const f16* pb = part + (size_t)bv * 32 * 64 + tid;
        float s = biasb[b * 64 + tid];
        #pragma unroll 8
        for (int sp = 0; sp < 32; ++sp)
            s += (float)pb[sp * 64];
        m_lds[tid] = s;
    } else if (tid < M + H) {
        h_lds[tid - M] = h[bv * H + (tid - M)];
    }
    __syncthreads();

    {
        float si = bih[tid], sh = bhh[tid];
        const float* wi = Wih + tid * M;
        const float* wh = Whh + tid * H;
        #pragma unroll 4
        for (int k = 0; k < M; ++k) si += wi[k] * m_lds[k];
        #pragma unroll 4
        for (int k = 0; k < H; ++k) sh += wh[k] * h_lds[k];
        gi[tid] = si;
        gh[tid] = sh;
    }
    __syncthreads();
    if (tid < H) {
        float r = 1.f / (1.f + expf(-(gi[tid] + gh[tid])));
        float z = 1.f / (1.f + expf(-(gi[H + tid] + gh[H + tid])));
        float n = tanhf(gi[2 * H + tid] + r * gh[2 * H + tid]);
        float hv = (1.f - z) * n + z * h_lds[tid];
        float maskf = (v < g_size[b]) ? 1.f : 0.f;
        hv *= maskf;
        h[bv * H + tid] = hv;
        h16[bv * H + tid] = (f16)hv;
    }
}

// -------------------------------------------------------------------------
// Readout via MFMA. 16-row blocks (128 blocks).
__global__ __launch_bounds__(256, 4) void readout_mfma(
    const f16* __restrict__ h16, const f16* __restrict__ hin16,
    const int* __restrict__ g_size, const f16* __restrict__ wp,
    const float* __restrict__ bi0, const float* __restrict__ bi1,
    const float* __restrict__ bi2, const float* __restrict__ bi3,
    const float* __restrict__ bj0, const float* __restrict__ bj1,
    const float* __restrict__ bj2, const float* __restrict__ bj3,
    float* __restrict__ contrib) {
    __shared__ f16 Xl[16][104];
    __shared__ f16 A1[16][136];
    __shared__ f16 A2[16][264];
    __shared__ float Gl[16][36];
    const f16* Ri0 = wp + OFF_RI0; const f16* Ri1 = wp + OFF_RI1;
    const f16* Ri2 = wp + OFF_RI2; const f16* Ri3 = wp + OFF_RI3;
    const f16* Rj0 = wp + OFF_RJ0; const f16* Rj1 = wp + OFF_RJ1;
    const f16* Rj2 = wp + OFF_RJ2; const f16* Rj3 = wp + OFF_RJ3;
    int tid = threadIdx.x, lane = tid & 63, wv = tid >> 6;
    int m = lane & 15, q = lane >> 4;
    int r0 = blockIdx.x * 16;

    {
        if (tid < 128) {
            int row = tid >> 3, pp = tid & 7;
            *(uint4*)&Xl[row][pp * 8] =
                *(const uint4*)(h16 + (size_t)(r0 + row) * 64 + pp * 8);
        }
        if (tid < 64) {
            int row2 = tid >> 2, p2 = tid & 3;
            *(uint4*)&Xl[row2][64 + p2 * 8] =
                *(const uint4*)(hin16 + (size_t)(r0 + row2) * 32 + p2 * 8);
        }
    }
    __syncthreads();

    // i-chain L0
    {
        f32x4 acc[2];
        acc[0] = (f32x4){0.f, 0.f, 0.f, 0.f};
        acc[1] = (f32x4){0.f, 0.f, 0.f, 0.f};
        #pragma unroll
        for (int s = 0; s < 3; ++s) {
            int k0 = s * 32 + q * 8;
            f16x8 afr = *(const f16x8*)&Xl[m][k0];
            #pragma unroll
            for (int ct = 0; ct < 2; ++ct) {
                f16x8 bfr = *(const f16x8*)(Ri0 + ((wv * 2 + ct) * 16 + m) * 96 + k0);
                acc[ct] = MFMA16(afr, bfr, acc[ct]);
            }
        }
        #pragma unroll
        for (int ct = 0; ct < 2; ++ct) {
            int n = (wv * 2 + ct) * 16 + m;
            float bb = bi0[n];
            #pragma unroll
            for (int r = 0; r < 4; ++r)
                A1[q * 4 + r][n] = (f16)fmaxf(acc[ct][r] + bb, 0.f);
        }
    }
    __syncthreads();

    // i-chain L1
    {
        f32x4 acc[4];
        #pragma unroll
        for (int ct = 0; ct < 4; ++ct) acc[ct] = (f32x4){0.f, 0.f, 0.f, 0.f};
        #pragma unroll
        for (int s = 0; s < 4; ++s) {
            int k0 = s * 32 + q * 8;
            f16x8 afr = *(const f16x8*)&A1[m][k0];
            #pragma unroll
            for (int ct = 0; ct < 4; ++ct) {
                f16x8 bfr = *(const f16x8*)(Ri1 + ((wv * 4 + ct) * 16 + m) * 128 + k0);
                acc[ct] = MFMA16(afr, bfr, acc[ct]);
            }
        }
        #pragma unroll
        for (int ct = 0; ct < 4; ++ct) {
            int n = (wv * 4 + ct) * 16 + m;
            float bb = bi1[n];
            #pragma unroll
            for (int r = 0; r < 4; ++r)
                A2[q * 4 + r][n] = (f16)fmaxf(acc[ct][r] + bb, 0.f);
        }
    }
    __syncthreads();

    // i-chain L2
    {
        f32x4 acc[2];
        acc[0] = (f32x4){0.f, 0.f, 0.f, 0.f};
        acc[1] = (f32x4){0.f, 0.f, 0.f, 0.f};
        #pragma unroll
        for (int s = 0; s < 8; ++s) {
            int k0 = s * 32 + q * 8;
            f16x8 afr = *(const f16x8*)&A2[m][k0];
            #pragma unroll
            for (int ct = 0; ct < 2; ++ct) {
                f16x8 bfr = *(const f16x8*)(Ri2 + ((wv * 2 + ct) * 16 + m) * 256 + k0);
                acc[ct] = MFMA16(afr, bfr, acc[ct]);
            }
        }
        __syncthreads();
        #pragma unroll
        for (int ct = 0; ct < 2; ++ct) {
            int n = (wv * 2 + ct) * 16 + m;
            float bb = bi2[n];
            #pragma unroll
            for (int r = 0; r < 4; ++r)
                A1[q * 4 + r][n] = (f16)fmaxf(acc[ct][r] + bb, 0.f);
        }
    }
    __syncthreads();

    // i-chain L3 -> gate
    if (wv < 2) {
        f32x4 acc = (f32x4){0.f, 0.f, 0.f, 0.f};
        int n = wv * 16 + m;
        #pragma unroll
        for (int s = 0; s < 4; ++s) {
            int k0 = s * 32 + q * 8;
            f16x8 bfr = *(const f16x8*)(Ri3 + n * 128 + k0);
            f16x8 afr = *(const f16x8*)&A1[m][k0];
            acc = MFMA16(afr, bfr, acc);
        }
        float bb = bi3[n];
        #pragma unroll
        for (int r = 0; r < 4; ++r)
            Gl[q * 4 + r][n] = 1.f / (1.f + expf(-(acc[r] + bb)));
    }
    __syncthreads();

    // j-chain L0
    {
        f32x4 acc[2];
        acc[0] = (f32x4){0.f, 0.f, 0.f, 0.f};
        acc[1] = (f32x4){0.f, 0.f, 0.f, 0.f};
        #pragma unroll
        for (int s = 0; s < 2; ++s) {
            int k0 = s * 32 + q * 8;
            f16x8 afr = *(const f16x8*)&Xl[m][k0];
            #pragma unroll
            for (int ct = 0; ct < 2; ++ct) {
                f16x8 bfr = *(const f16x8*)(Rj0 + ((wv * 2 + ct) * 16 + m) * 64 + k0);
                acc[ct] = MFMA16(afr, bfr, acc[ct]);
            }
        }
        __syncthreads();
        #pragma unroll
        for (int ct = 0; ct < 2; ++ct) {
            int n = (wv * 2 + ct) * 16 + m;
            float bb = bj0[n];
            #pragma unroll
            for (int r = 0; r < 4; ++r)
                A1[q * 4 + r][n] = (f16)fmaxf(acc[ct][r] + bb, 0.f);
        }
    }
    __syncthreads();

    // j-chain L1
    {
        f32x4 acc[4];
        #pragma unroll
        for (int ct = 0; ct < 4; ++ct) acc[ct] = (f32x4){0.f, 0.f, 0.f, 0.f};
        #pragma unroll
        for (int s = 0; s < 4; ++s) {
            int k0 = s * 32 + q * 8;
            f16x8 afr = *(const f16x8*)&A1[m][k0];
            #pragma unroll
            for (int ct = 0; ct < 4; ++ct) {
                f16x8 bfr = *(const f16x8*)(Rj1 + ((wv * 4 + ct) * 16 + m) * 128 + k0);
                acc[ct] = MFMA16(afr, bfr, acc[ct]);
            }
        }
        #pragma unroll
        for (int ct = 0; ct < 4; ++ct) {
            int n = (wv * 4 + ct) * 16 + m;
            float bb = bj1[n];
            #pragma unroll
            for (int r = 0; r < 4; ++r)
                A2[q * 4 + r][n] = (f16)fmaxf(acc[ct][r] + bb, 0.f);
        }
    }
    __syncthreads();

    // j-chain L2
    {
        f32x4 acc[2];
        acc[0] = (f32x4){0.f, 0.f, 0.f, 0.f};
        acc[1] = (f32x4){0.f, 0.f, 0.f, 0.f};
        #pragma unroll
        for (int s = 0; s < 8; ++s) {
            int k0 = s * 32 + q * 8;
            f16x8 afr = *(const f16x8*)&A2[m][k0];
            #pragma unroll
            for (int ct = 0; ct < 2; ++ct) {
                f16x8 bfr = *(const f16x8*)(Rj2 + ((wv * 2 + ct) * 16 + m) * 256 + k0);
                acc[ct] = MFMA16(afr, bfr, acc[ct]);
            }
        }
        __syncthreads();
        #pragma unroll
        for (int ct = 0; ct < 2; ++ct) {
            int n = (wv * 2 + ct) * 16 + m;
            float bb = bj2[n];
            #pragma unroll
            for (int r = 0; r < 4; ++r)
                A1[q * 4 + r][n] = (f16)fmaxf(acc[ct][r] + bb, 0.f);
        }
    }
    __syncthreads();

    // j-chain L3 + combine
    if (wv < 2) {
        f32x4 acc = (f32x4){0.f, 0.f, 0.f, 0.f};
        int n = wv * 16 + m;
        #pragma unroll
        for (int s = 0; s < 4; ++s) {
            int k0 = s * 32 + q * 8;
            f16x8 bfr = *(const f16x8*)(Rj3 + n * 128 + k0);
            f16x8 afr = *(const f16x8*)&A1[m][k0];
            acc = MFMA16(afr, bfr, acc);
        }
        float bb = bj3[n];
        #pragma unroll
        for (int r = 0; r < 4; ++r) {
            int row = q * 4 + r;
            int rg = r0 + row;
            int b = rg >> 7, v = rg & 127;
            float maskf = (v < g_size[b]) ? 1.f : 0.f;
            contrib[(size_t)rg * T + n] = maskf * Gl[row][n] * (acc[r] + bb);
        }
    }
}

// -------------------------------------------------------------------------
__global__ __launch_bounds__(64) void finalize_kernel(const float* __restrict__ contrib,
                                                      float* __restrict__ out) {
    __shared__ float res[T];
    int b = blockIdx.x;
    int o = threadIdx.x;
    if (o < T) {
        float s = 0.f;
        for (int v = 0; v < N; ++v) s += contrib[(b * N + v) * T + o];
        res[o] = s;
    }
    __syncthreads();
    if (o < T) {
        float mx = res[0];
        for (int i = 1; i < T; ++i) mx = fmaxf(mx, res[i]);
        float se = 0.f;
        for (int i = 0; i < T; ++i) se += expf(res[i] - mx);
        out[b * T + o] = res[o] - mx - logf(se);
    }
}

// -------------------------------------------------------------------------
extern "C" void kernel_launch(void* const* d_in, const int* in_sizes, int n_in,
                              void* d_out, int out_size, void* d_ws, size_t ws_size,
                              hipStream_t stream) {
    (void)in_sizes; (void)n_in; (void)out_size; (void)ws_size;
    const float* h_in = (const float*)d_in[0];
    const float* am   = (const float*)d_in[1];
    const int*   g_sz = (const int*)d_in[2];
    const float* We0 = (const float*)d_in[3],  *be0 = (const float*)d_in[4];
    const float* We1 = (const float*)d_in[5],  *be1 = (const float*)d_in[6];
    const float* We2 = (const float*)d_in[7],  *be2 = (const float*)d_in[8];
    const float* We3 = (const float*)d_in[9],  *be3 = (const float*)d_in[10];
    const float* Wih = (const float*)d_in[11], *Whh = (const float*)d_in[12];
    const float* bih = (const float*)d_in[13], *bhh = (const float*)d_in[14];
    const float* Wi0 = (const float*)d_in[15], *bi0 = (const float*)d_in[16];
    const float* Wj0 = (const float*)d_in[17], *bj0 = (const float*)d_in[18];
    const float* Wi1 = (const float*)d_in[19], *bi1 = (const float*)d_in[20];
    const float* Wj1 = (const float*)d_in[21], *bj1 = (const float*)d_in[22];
    const float* Wi2 = (const float*)d_in[23], *bi2 = (const float*)d_in[24];
    const float* Wj2 = (const float*)d_in[25], *bj2 = (const float*)d_in[26];
    const float* Wi3 = (const float*)d_in[27], *bi3 = (const float*)d_in[28];
    const float* Wj3 = (const float*)d_in[29], *bj3 = (const float*)d_in[30];

    float* out = (float*)d_out;

    // workspace layout (~110 MB); part f16
    f16*   f    = (f16*)d_ws;                             // 33554432 halves
    f16*   P2   = f + (size_t)33554432;                   // 16777216 halves
    f16*   part = P2 + (size_t)16777216;                  // 4194304 halves
    float* h    = (float*)(part + (size_t)4194304);       // 131072
    float* biasb = h + 131072;                            // 1024
    float* contrib = biasb + 1024;                        // 65536
    f16*   h16  = (f16*)(contrib + 65536);                // 131072 halves
    f16*   hin16 = h16 + 131072;                          // 65536 halves
    f16*   wp   = hin16 + 65536;                          // 749568 halves

    prep_kernel<<<(WPACK_SZ + 255) / 256, 256, 0, stream>>>(
        h_in, We1, We2, We3, Wi0, Wi1, Wi2, Wi3, Wj0, Wj1, Wj2, Wj3,
        h, h16, hin16, wp);

    // layer 0: edge + p_gemm + bias fused into one launch
    mega0_kernel<<<4096 + 1024 + 16, 256, 0, stream>>>(
        am, We0, be0, be1, be2, be3, wp, h, h16, f, P2, biasb);
    msg_mfma<<<dim3(32, 16), 256, 0, stream>>>(f, P2, part);
    gru_kernel<<<B * N, 192, 0, stream>>>(biasb, part, h, h16,
                                          Wih, Whh, bih, bhh, g_sz);

    for (int l = 1; l < 3; ++l) {
        pg_bias_kernel<<<1024 + 16, 256, 0, stream>>>(be3, wp, h, h16, P2, biasb);
        msg_mfma<<<dim3(32, 16), 256, 0, stream>>>(f, P2, part);
        gru_kernel<<<B * N, 192, 0, stream>>>(biasb, part, h, h16,
                                              Wih, Whh, bih, bhh, g_sz);
    }

    readout_mfma<<<128, 256, 0, stream>>>(h16, hin16, g_sz, wp,
                                          bi0, bi1, bi2, bi3,
                                          bj0, bj1, bj2, bj3, contrib);
    finalize_kernel<<<B, 64, 0, stream>>>(contrib, out);
}

// Round 8
// 383.677 us; speedup vs baseline: 1.0228x; 1.0200x over previous
//
#include <hip/hip_runtime.h>
#include <math.h>

// Problem constants
#define B   16
#define N   128
#define E   4
#define H   64
#define M   64
#define IN_ 32
#define T   32
#define K1  128
#define K2  256
#define K3  128

typedef _Float16 f16;
typedef f16  f16x8 __attribute__((ext_vector_type(8)));
typedef f16  f16x4 __attribute__((ext_vector_type(4)));
typedef f16  f16x2 __attribute__((ext_vector_type(2)));
typedef float f32x4 __attribute__((ext_vector_type(4)));

#define MFMA16(a, b, c) __builtin_amdgcn_mfma_f32_16x16x32_f16(a, b, c, 0, 0, 0)

// fp16 weight pack offsets (halves)
#define OFF_W1T   0
#define OFF_W2T   32768
#define OFF_WE3H  65536
#define OFF_RI0   589824
#define OFF_RI1   602112
#define OFF_RI2   634880
#define OFF_RI3   667648
#define OFF_RJ0   671744
#define OFF_RJ1   679936
#define OFF_RJ2   712704
#define OFF_RJ3   745472
#define WPACK_SZ  749568

// R14: eliminate zero-reuse LDS staging. Audit: a staged tile pays only if
// read >1x. msg's Al (read at wv-dependent rows -> once) and pgemm's Bl
// (wv-dependent -> once) were pure LDS round-trip overhead; both now load
// fragments direct from global (f is L3-resident, We3h is L2-resident),
// issued before the barrier so latency hides under the Bl/Al staging.
// msg's Bl and pgemm's Al keep 4x cross-wave reuse -> stay in LDS.
// part layout reverted to R11 [sp][bv][o] (R13 relayout was noise-negative).
union SmemU {
    struct { float xl[64][4]; f16 y1[64][136]; f16 y2[64][264]; } e;   // 52224
    union { f16 Al[128][72]; f16 Ol[128][136]; } pg;                   // 34816
    struct { float prt[4][64]; float hsum[64]; float bias[64]; } bi;   // 1536
};

// -------------------------------------------------------------------------
// prep: pad h (fp32/fp16 + hin16) AND build fp16 weight pack. One launch.
__global__ __launch_bounds__(256) void prep_kernel(
    const float* __restrict__ h_in,
    const float* __restrict__ We1, const float* __restrict__ We2,
    const float* __restrict__ We3,
    const float* __restrict__ Wi0, const float* __restrict__ Wi1,
    const float* __restrict__ Wi2, const float* __restrict__ Wi3,
    const float* __restrict__ Wj0, const float* __restrict__ Wj1,
    const float* __restrict__ Wj2, const float* __restrict__ Wj3,
    float* __restrict__ h, f16* __restrict__ h16, f16* __restrict__ hin16,
    f16* __restrict__ wp) {
    int idx = blockIdx.x * 256 + threadIdx.x;
    if (idx < B * N * H) {
        int i  = idx & (H - 1);
        int bn = idx >> 6;
        float v = (i < IN_) ? h_in[bn * IN_ + i] : 0.f;
        h[idx] = v;
        h16[idx] = (f16)v;
        if (i < IN_) hin16[bn * IN_ + i] = (f16)v;
    }
    if (idx >= WPACK_SZ) return;
    if (idx < OFF_W2T) {                          // W1t [256][128]
        int j = idx >> 7, k = idx & 127;
        wp[idx] = (f16)We1[k * 256 + j];
    } else if (idx < OFF_WE3H) {                  // W2t [128][256]
        int t = idx - OFF_W2T;
        int j = t >> 8, k = t & 255;
        wp[idx] = (f16)We2[k * 128 + j];
    } else if (idx < OFF_RI0) {                   // We3h copy
        wp[idx] = (f16)We3[idx - OFF_WE3H];
    } else if (idx < OFF_RI1) {                   // Ri0 [128][96]
        int t = idx - OFF_RI0;
        int n = t / 96, c = t % 96;
        wp[idx] = (f16)Wi0[c * 128 + n];
    } else if (idx < OFF_RI2) {                   // Ri1 [256][128]
        int t = idx - OFF_RI1;
        int n = t >> 7, k = t & 127;
        wp[idx] = (f16)Wi1[k * 256 + n];
    } else if (idx < OFF_RI3) {                   // Ri2 [128][256]
        int t = idx - OFF_RI2;
        int n = t >> 8, k = t & 255;
        wp[idx] = (f16)Wi2[k * 128 + n];
    } else if (idx < OFF_RJ0) {                   // Ri3 [32][128]
        int t = idx - OFF_RI3;
        int n = t >> 7, k = t & 127;
        wp[idx] = (f16)Wi3[k * 32 + n];
    } else if (idx < OFF_RJ1) {                   // Rj0 [128][64]
        int t = idx - OFF_RJ0;
        int n = t >> 6, c = t & 63;
        wp[idx] = (f16)Wj0[c * 128 + n];
    } else if (idx < OFF_RJ2) {                   // Rj1 [256][128]
        int t = idx - OFF_RJ1;
        int n = t >> 7, k = t & 127;
        wp[idx] = (f16)Wj1[k * 256 + n];
    } else if (idx < OFF_RJ3) {                   // Rj2 [128][256]
        int t = idx - OFF_RJ2;
        int n = t >> 8, k = t & 255;
        wp[idx] = (f16)Wj2[k * 128 + n];
    } else {                                      // Rj3 [32][128]
        int t = idx - OFF_RJ3;
        int n = t >> 7, k = t & 127;
        wp[idx] = (f16)Wj3[k * 32 + n];
    }
}

// ===================== task bodies (256 threads) ===========================

__device__ void edge_body(SmemU& su, int tid, int tile,
                          const float* __restrict__ am,
                          const float* __restrict__ We0,
                          const float* __restrict__ be0,
                          const f16* __restrict__ W1t,
                          const float* __restrict__ be1,
                          const f16* __restrict__ W2t,
                          const float* __restrict__ be2,
                          f16* __restrict__ f) {
    int lane = tid & 63, wv = tid >> 6;
    long long g0 = (long long)tile * 64;

    ((float*)su.e.xl)[tid] = am[g0 * 4 + tid];
    __syncthreads();

    {   // layer 1: K=4, VALU. 2 consecutive features x 16 edges per thread;
        // packed dword writes (lane-linear banks).
        int j0 = (tid & 63) * 2, e0 = (tid >> 6) * 16;
        float w00 = We0[j0],       w01 = We0[j0 + 1];
        float w10 = We0[128 + j0], w11 = We0[128 + j0 + 1];
        float w20 = We0[256 + j0], w21 = We0[256 + j0 + 1];
        float w30 = We0[384 + j0], w31 = We0[384 + j0 + 1];
        float b0 = be0[j0], b1 = be0[j0 + 1];
        #pragma unroll 4
        for (int e = e0; e < e0 + 16; ++e) {
            float x0 = su.e.xl[e][0], x1 = su.e.xl[e][1];
            float x2 = su.e.xl[e][2], x3 = su.e.xl[e][3];
            float v0 = b0 + x0 * w00 + x1 * w10 + x2 * w20 + x3 * w30;
            float v1 = b1 + x0 * w01 + x1 * w11 + x2 * w21 + x3 * w31;
            f16x2 p;
            p[0] = (f16)fmaxf(v0, 0.f);
            p[1] = (f16)fmaxf(v1, 0.f);
            *(f16x2*)&su.e.y1[e][j0] = p;
        }
    }
    __syncthreads();

    int m = lane & 15, q = lane >> 4;

    {   // layer 2 (operand-swapped: A=weights, B=activations)
        f32x4 acc[4][4];
        #pragma unroll
        for (int ct = 0; ct < 4; ++ct)
            #pragma unroll
            for (int rt = 0; rt < 4; ++rt) acc[ct][rt] = (f32x4){0.f, 0.f, 0.f, 0.f};
        #pragma unroll
        for (int s = 0; s < 4; ++s) {
            int k0 = s * 32 + q * 8;
            f16x8 afr[4], bfr[4];
            #pragma unroll
            for (int rt = 0; rt < 4; ++rt)
                afr[rt] = *(const f16x8*)&su.e.y1[rt * 16 + m][k0];
            #pragma unroll
            for (int ct = 0; ct < 4; ++ct) {
                int n = (wv * 4 + ct) * 16 + m;
                bfr[ct] = *(const f16x8*)(W1t + n * 128 + k0);
            }
            #pragma unroll
            for (int ct = 0; ct < 4; ++ct)
                #pragma unroll
                for (int rt = 0; rt < 4; ++rt)
                    acc[ct][rt] = MFMA16(bfr[ct], afr[rt], acc[ct][rt]);
        }
        // D: col = e (lane m), rows = 4 consecutive n -> packed 8B stores
        #pragma unroll
        for (int ct = 0; ct < 4; ++ct) {
            int n0 = (wv * 4 + ct) * 16 + q * 4;
            f32x4 bb = *(const f32x4*)&be1[n0];
            #pragma unroll
            for (int rt = 0; rt < 4; ++rt) {
                int e = rt * 16 + m;
                f16x4 pk;
                #pragma unroll
                for (int r = 0; r < 4; ++r)
                    pk[r] = (f16)fmaxf(acc[ct][rt][r] + bb[r], 0.f);
                *(f16x4*)&su.e.y2[e][n0] = pk;
            }
        }
    }
    __syncthreads();

    {   // layer 3 (operand-swapped; out-stage back into y1)
        f32x4 acc[2][4];
        #pragma unroll
        for (int ct = 0; ct < 2; ++ct)
            #pragma unroll
            for (int rt = 0; rt < 4; ++rt) acc[ct][rt] = (f32x4){0.f, 0.f, 0.f, 0.f};
        #pragma unroll
        for (int s = 0; s < 8; ++s) {
            int k0 = s * 32 + q * 8;
            f16x8 afr[4], bfr[2];
            #pragma unroll
            for (int rt = 0; rt < 4; ++rt)
                afr[rt] = *(const f16x8*)&su.e.y2[rt * 16 + m][k0];
            #pragma unroll
            for (int ct = 0; ct < 2; ++ct) {
                int n = (wv * 2 + ct) * 16 + m;
                bfr[ct] = *(const f16x8*)(W2t + n * 256 + k0);
            }
            #pragma unroll
            for (int ct = 0; ct < 2; ++ct)
                #pragma unroll
                for (int rt = 0; rt < 4; ++rt)
                    acc[ct][rt] = MFMA16(bfr[ct], afr[rt], acc[ct][rt]);
        }
        #pragma unroll
        for (int ct = 0; ct < 2; ++ct) {
            int n0 = (wv * 2 + ct) * 16 + q * 4;
            f32x4 bb = *(const f32x4*)&be2[n0];
            #pragma unroll
            for (int rt = 0; rt < 4; ++rt) {
                int e = rt * 16 + m;
                f16x4 pk;
                #pragma unroll
                for (int r = 0; r < 4; ++r)
                    pk[r] = (f16)fmaxf(acc[ct][rt][r] + bb[r], 0.f);
                *(f16x4*)&su.e.y1[e][n0] = pk;
            }
        }
    }
    __syncthreads();

    #pragma unroll
    for (int j = 0; j < 4; ++j) {
        int c = tid + j * 256;
        int e = c >> 4, pp = c & 15;
        *(uint4*)(f + (g0 + e) * 128 + pp * 8) = *(const uint4*)&su.e.y1[e][pp * 8];
    }
}

// pgemm: Al (4x cross-wave reuse) staged in LDS; Bl (zero reuse) loaded
// direct from L2-resident We3h into registers, issued before the barrier.
__device__ void pgemm_body(SmemU& su, int tid, int ob, int nt,
                           const f16* __restrict__ h16,
                           const f16* __restrict__ We3h,
                           f16* __restrict__ P2) {
    int lane = tid & 63, wv = tid >> 6;
    int m = lane & 15, q = lane >> 4;

    #pragma unroll
    for (int j = 0; j < 4; ++j) {
        int c = tid + j * 256;
        int row = c >> 3, pp = c & 7;
        *(uint4*)&su.pg.Al[row][pp * 8] =
            *(const uint4*)(h16 + (size_t)(nt * 128 + row) * 64 + pp * 8);
    }
    // Bl bypass: 4 fragments/thread, direct from We3h (read once each).
    f16x8 bfr[2][2];                               // [ct][s]
    #pragma unroll
    for (int ct = 0; ct < 2; ++ct) {
        int c3 = (wv * 2 + ct) * 16 + m;
        #pragma unroll
        for (int s = 0; s < 2; ++s)
            bfr[ct][s] = *(const f16x8*)(We3h + ((size_t)(c3 * 64 + ob)) * 64
                                               + s * 32 + q * 8);
    }
    __syncthreads();

    f32x4 acc[2][8];
    #pragma unroll
    for (int ct = 0; ct < 2; ++ct)
        #pragma unroll
        for (int rt = 0; rt < 8; ++rt) acc[ct][rt] = (f32x4){0.f, 0.f, 0.f, 0.f};
    #pragma unroll
    for (int s = 0; s < 2; ++s) {
        int k0 = s * 32 + q * 8;
        f16x8 afr[8];
        #pragma unroll
        for (int rt = 0; rt < 8; ++rt)
            afr[rt] = *(const f16x8*)&su.pg.Al[rt * 16 + m][k0];
        #pragma unroll
        for (int ct = 0; ct < 2; ++ct)
            #pragma unroll
            for (int rt = 0; rt < 8; ++rt)
                acc[ct][rt] = MFMA16(bfr[ct][s], afr[rt], acc[ct][rt]);
    }
    // All threads done READING Al before Ol (which aliases it) is written.
    __syncthreads();
    // D: col = v (lane m), rows = 4 consecutive c -> packed 8B stores
    #pragma unroll
    for (int ct = 0; ct < 2; ++ct) {
        int c0 = (wv * 2 + ct) * 16 + q * 4;
        #pragma unroll
        for (int rt = 0; rt < 8; ++rt) {
            int v = rt * 16 + m;
            f16x4 pk;
            #pragma unroll
            for (int r = 0; r < 4; ++r) pk[r] = (f16)acc[ct][rt][r];
            *(f16x4*)&su.pg.Ol[v][c0] = pk;
        }
    }
    __syncthreads();
    #pragma unroll
    for (int j = 0; j < 8; ++j) {
        int c = tid + j * 256;
        int row = c >> 4, pp = c & 15;
        *(uint4*)(P2 + ((size_t)(nt * 128 + row) * 64 + ob) * 128 + pp * 8) =
            *(const uint4*)&su.pg.Ol[row][pp * 8];
    }
}

// bias: biasb[b,o] = sum_i be3[o*64+i] * (sum_w h[b,w,i])
__device__ void bias_body(SmemU& su, int tid, int b,
                          const float* __restrict__ h,
                          const float* __restrict__ be3,
                          float* __restrict__ biasb) {
    int i = tid & 63, wq = tid >> 6;
    float s = 0.f;
    for (int w = wq; w < N; w += 4) s += h[((size_t)(b * N + w)) * H + i];
    su.bi.prt[wq][i] = s;
    __syncthreads();
    if (tid < 64)
        su.bi.hsum[tid] = su.bi.prt[0][tid] + su.bi.prt[1][tid]
                        + su.bi.prt[2][tid] + su.bi.prt[3][tid];
    __syncthreads();
    if (tid < 64) {
        float sb = 0.f;
        #pragma unroll 4
        for (int ii = 0; ii < H; ++ii) sb += be3[tid * H + ii] * su.bi.hsum[ii];
        biasb[b * 64 + tid] = sb;
    }
}

// -------------------------------------------------------------------------
// mega0: edge tiles (0..4095) + L0 p_gemm (4096..5119) + L0 bias (5120..5135)
__global__ __launch_bounds__(256, 3) void mega0_kernel(
    const float* __restrict__ am,
    const float* __restrict__ We0, const float* __restrict__ be0,
    const float* __restrict__ be1, const float* __restrict__ be2,
    const float* __restrict__ be3,
    const f16* __restrict__ wp,
    const float* __restrict__ h, const f16* __restrict__ h16,
    f16* __restrict__ f, f16* __restrict__ P2, float* __restrict__ biasb) {
    __shared__ SmemU su;
    int tid = threadIdx.x;
    int bid = blockIdx.x;
    if (bid < 4096) {
        edge_body(su, tid, bid, am, We0, be0, wp + OFF_W1T, be1, wp + OFF_W2T,
                  be2, f);
    } else if (bid < 5120) {
        int t = bid - 4096;
        pgemm_body(su, tid, t & 63, t >> 6, h16, wp + OFF_WE3H, P2);
    } else {
        bias_body(su, tid, bid - 5120, h, be3, biasb);
    }
}

// pg_bias: p_gemm (0..1023) + bias (1024..1039), for layers 1,2
__global__ __launch_bounds__(256, 3) void pg_bias_kernel(
    const float* __restrict__ be3, const f16* __restrict__ wp,
    const float* __restrict__ h, const f16* __restrict__ h16,
    f16* __restrict__ P2, float* __restrict__ biasb) {
    __shared__ SmemU su;
    int tid = threadIdx.x;
    int bid = blockIdx.x;
    if (bid < 1024) {
        pgemm_body(su, tid, bid & 63, bid >> 6, h16, wp + OFF_WE3H, P2);
    } else {
        bias_body(su, tid, bid - 1024, h, be3, biasb);
    }
}

// -------------------------------------------------------------------------
// msg GEMM: part[ws][(b,v),o] = sum_{w in split} sum_k f[(b,v),w,k]*P2[(b,w),o,k]
// R14: Al bypassed (zero reuse) -> direct per-lane fragment loads from
// L3-resident f, issued before Bl's barrier. Bl (4x reuse) stays in LDS.
__global__ __launch_bounds__(256, 3) void msg_mfma(
    const f16* __restrict__ f, const f16* __restrict__ P2,
    f16* __restrict__ part) {
    __shared__ f16 Bl[64][136];
    int tid = threadIdx.x, lane = tid & 63, wv = tid >> 6;
    int ws = blockIdx.x;
    int b  = blockIdx.y;
    int m = lane & 15, q = lane >> 4;

    f32x4 acc[2][4];
    #pragma unroll
    for (int rt = 0; rt < 2; ++rt)
        #pragma unroll
        for (int ct = 0; ct < 4; ++ct) acc[rt][ct] = (f32x4){0.f, 0.f, 0.f, 0.f};

    for (int wi = 0; wi < 4; ++wi) {
        int w = ws * 4 + wi;
        // stage Bl (each element consumed by all 4 waves)
        #pragma unroll
        for (int j = 0; j < 4; ++j) {
            int c = tid + j * 256;
            int o = c >> 4, pp = c & 15;
            *(uint4*)&Bl[o][pp * 8] =
                *(const uint4*)(P2 + (((size_t)(b * 128 + w) * 64 + o) * 128) + pp * 8);
        }
        // Al bypass: 8 fragments/thread direct from f (each read exactly once)
        f16x8 afr[2][4];                           // [rt][s]
        #pragma unroll
        for (int rt = 0; rt < 2; ++rt) {
            int v = (wv * 2 + rt) * 16 + m;
            const f16* fr = f + ((size_t)(b * 128 + v) * 128 + w) * 128;
            #pragma unroll
            for (int s = 0; s < 4; ++s)
                afr[rt][s] = *(const f16x8*)(fr + s * 32 + q * 8);
        }
        __syncthreads();
        #pragma unroll
        for (int s = 0; s < 4; ++s) {
            int k0 = s * 32 + q * 8;
            f16x8 bfr[4];
            #pragma unroll
            for (int ct = 0; ct < 4; ++ct)
                bfr[ct] = *(const f16x8*)&Bl[ct * 16 + m][k0];
            #pragma unroll
            for (int rt = 0; rt < 2; ++rt)
                #pragma unroll
                for (int ct = 0; ct < 4; ++ct)
                    acc[rt][ct] = MFMA16(afr[rt][s], bfr[ct], acc[rt][ct]);
        }
        __syncthreads();   // all Bl reads done before next wi overwrites
    }
    f16* pp = part + (size_t)ws * (2048 * 64);
    #pragma unroll
    for (int rt = 0; rt < 2; ++rt)
        #pragma unroll
        for (int ct = 0; ct < 4; ++ct) {
            int o = ct * 16 + m;
            #pragma unroll
            for (int r = 0; r < 4; ++r) {
                int v = (wv * 2 + rt) * 16 + q * 4 + r;
                pp[(size_t)(b * 128 + v) * 64 + o] = (f16)acc[rt][ct][r];
            }
        }
}

// -------------------------------------------------------------------------
// GRU: msg = biasb[b] + sum of 32 partials (f16); torch GRU step; mask.
__global__ __launch_bounds__(192) void gru_kernel(
    const float* __restrict__ biasb, const f16* __restrict__ part,
    float* __restrict__ h, f16* __restrict__ h16,
    const float* __restrict__ Wih, const float* __restrict__ Whh,
    const float* __restrict__ bih, const float* __restrict__ bhh,
    const int* __restrict__ g_size) {
    __shared__ float m_lds[M];
    __shared__ float h_lds[H];
    __shared__ float gi[3 * H], gh[3 * H];
    int tid = threadIdx.x;
    int bv  = blockIdx.x;
    int b = bv >> 7, v = bv & 127;

    if (tid < M) {
        float s = biasb[b * 64 + tid];
        #pragma unroll 8
        for (int sp = 0; sp < 32; ++sp)
            s += (float)part[(size_t)sp * (2048 * 64) + bv * 64 + tid];
        m_lds[tid] = s;
    } else if (tid < M + H) {
        h_lds[tid - M] = h[bv * H + (tid - M)];
    }
    __syncthreads();

    {
        float si = bih[tid], sh = bhh[tid];
        const float* wi = Wih + tid * M;
        const float* wh = Whh + tid * H;
        #pragma unroll 4
        for (int k = 0; k < M; ++k) si += wi[k] * m_lds[k];
        #pragma unroll 4
        for (int k = 0; k < H; ++k) sh += wh[k] * h_lds[k];
        gi[tid] = si;
        gh[tid] = sh;
    }
    __syncthreads();
    if (tid < H) {
        float r = 1.f / (1.f + expf(-(gi[tid] + gh[tid])));
        float z = 1.f / (1.f + expf(-(gi[H + tid] + gh[H + tid])));
        float n = tanhf(gi[2 * H + tid] + r * gh[2 * H + tid]);
        float hv = (1.f - z) * n + z * h_lds[tid];
        float maskf = (v < g_size[b]) ? 1.f : 0.f;
        hv *= maskf;
        h[bv * H + tid] = hv;
        h16[bv * H + tid] = (f16)hv;
    }
}

// -------------------------------------------------------------------------
// Readout via MFMA. 16-row blocks (128 blocks).
__global__ __launch_bounds__(256, 4) void readout_mfma(
    const f16* __restrict__ h16, const f16* __restrict__ hin16,
    const int* __restrict__ g_size, const f16* __restrict__ wp,
    const float* __restrict__ bi0, const float* __restrict__ bi1,
    const float* __restrict__ bi2, const float* __restrict__ bi3,
    const float* __restrict__ bj0, const float* __restrict__ bj1,
    const float* __restrict__ bj2, const float* __restrict__ bj3,
    float* __restrict__ contrib) {
    __shared__ f16 Xl[16][104];
    __shared__ f16 A1[16][136];
    __shared__ f16 A2[16][264];
    __shared__ float Gl[16][36];
    const f16* Ri0 = wp + OFF_RI0; const f16* Ri1 = wp + OFF_RI1;
    const f16* Ri2 = wp + OFF_RI2; const f16* Ri3 = wp + OFF_RI3;
    const f16* Rj0 = wp + OFF_RJ0; const f16* Rj1 = wp + OFF_RJ1;
    const f16* Rj2 = wp + OFF_RJ2; const f16* Rj3 = wp + OFF_RJ3;
    int tid = threadIdx.x, lane = tid & 63, wv = tid >> 6;
    int m = lane & 15, q = lane >> 4;
    int r0 = blockIdx.x * 16;

    {
        if (tid < 128) {
            int row = tid >> 3, pp = tid & 7;
            *(uint4*)&Xl[row][pp * 8] =
                *(const uint4*)(h16 + (size_t)(r0 + row) * 64 + pp * 8);
        }
        if (tid < 64) {
            int row2 = tid >> 2, p2 = tid & 3;
            *(uint4*)&Xl[row2][64 + p2 * 8] =
                *(const uint4*)(hin16 + (size_t)(r0 + row2) * 32 + p2 * 8);
        }
    }
    __syncthreads();

    // i-chain L0
    {
        f32x4 acc[2];
        acc[0] = (f32x4){0.f, 0.f, 0.f, 0.f};
        acc[1] = (f32x4){0.f, 0.f, 0.f, 0.f};
        #pragma unroll
        for (int s = 0; s < 3; ++s) {
            int k0 = s * 32 + q * 8;
            f16x8 afr = *(const f16x8*)&Xl[m][k0];
            #pragma unroll
            for (int ct = 0; ct < 2; ++ct) {
                f16x8 bfr = *(const f16x8*)(Ri0 + ((wv * 2 + ct) * 16 + m) * 96 + k0);
                acc[ct] = MFMA16(afr, bfr, acc[ct]);
            }
        }
        #pragma unroll
        for (int ct = 0; ct < 2; ++ct) {
            int n = (wv * 2 + ct) * 16 + m;
            float bb = bi0[n];
            #pragma unroll
            for (int r = 0; r < 4; ++r)
                A1[q * 4 + r][n] = (f16)fmaxf(acc[ct][r] + bb, 0.f);
        }
    }
    __syncthreads();

    // i-chain L1
    {
        f32x4 acc[4];
        #pragma unroll
        for (int ct = 0; ct < 4; ++ct) acc[ct] = (f32x4){0.f, 0.f, 0.f, 0.f};
        #pragma unroll
        for (int s = 0; s < 4; ++s) {
            int k0 = s * 32 + q * 8;
            f16x8 afr = *(const f16x8*)&A1[m][k0];
            #pragma unroll
            for (int ct = 0; ct < 4; ++ct) {
                f16x8 bfr = *(const f16x8*)(Ri1 + ((wv * 4 + ct) * 16 + m) * 128 + k0);
                acc[ct] = MFMA16(afr, bfr, acc[ct]);
            }
        }
        #pragma unroll
        for (int ct = 0; ct < 4; ++ct) {
            int n = (wv * 4 + ct) * 16 + m;
            float bb = bi1[n];
            #pragma unroll
            for (int r = 0; r < 4; ++r)
                A2[q * 4 + r][n] = (f16)fmaxf(acc[ct][r] + bb, 0.f);
        }
    }
    __syncthreads();

    // i-chain L2
    {
        f32x4 acc[2];
        acc[0] = (f32x4){0.f, 0.f, 0.f, 0.f};
        acc[1] = (f32x4){0.f, 0.f, 0.f, 0.f};
        #pragma unroll
        for (int s = 0; s < 8; ++s) {
            int k0 = s * 32 + q * 8;
            f16x8 afr = *(const f16x8*)&A2[m][k0];
            #pragma unroll
            for (int ct = 0; ct < 2; ++ct) {
                f16x8 bfr = *(const f16x8*)(Ri2 + ((wv * 2 + ct) * 16 + m) * 256 + k0);
                acc[ct] = MFMA16(afr, bfr, acc[ct]);
            }
        }
        __syncthreads();
        #pragma unroll
        for (int ct = 0; ct < 2; ++ct) {
            int n = (wv * 2 + ct) * 16 + m;
            float bb = bi2[n];
            #pragma unroll
            for (int r = 0; r < 4; ++r)
                A1[q * 4 + r][n] = (f16)fmaxf(acc[ct][r] + bb, 0.f);
        }
    }
    __syncthreads();

    // i-chain L3 -> gate
    if (wv < 2) {
        f32x4 acc = (f32x4){0.f, 0.f, 0.f, 0.f};
        int n = wv * 16 + m;
        #pragma unroll
        for (int s = 0; s < 4; ++s) {
            int k0 = s * 32 + q * 8;
            f16x8 bfr = *(const f16x8*)(Ri3 + n * 128 + k0);
            f16x8 afr = *(const f16x8*)&A1[m][k0];
            acc = MFMA16(afr, bfr, acc);
        }
        float bb = bi3[n];
        #pragma unroll
        for (int r = 0; r < 4; ++r)
            Gl[q * 4 + r][n] = 1.f / (1.f + expf(-(acc[r] + bb)));
    }
    __syncthreads();

    // j-chain L0
    {
        f32x4 acc[2];
        acc[0] = (f32x4){0.f, 0.f, 0.f, 0.f};
        acc[1] = (f32x4){0.f, 0.f, 0.f, 0.f};
        #pragma unroll
        for (int s = 0; s < 2; ++s) {
            int k0 = s * 32 + q * 8;
            f16x8 afr = *(const f16x8*)&Xl[m][k0];
            #pragma unroll
            for (int ct = 0; ct < 2; ++ct) {
                f16x8 bfr = *(const f16x8*)(Rj0 + ((wv * 2 + ct) * 16 + m) * 64 + k0);
                acc[ct] = MFMA16(afr, bfr, acc[ct]);
            }
        }
        __syncthreads();
        #pragma unroll
        for (int ct = 0; ct < 2; ++ct) {
            int n = (wv * 2 + ct) * 16 + m;
            float bb = bj0[n];
            #pragma unroll
            for (int r = 0; r < 4; ++r)
                A1[q * 4 + r][n] = (f16)fmaxf(acc[ct][r] + bb, 0.f);
        }
    }
    __syncthreads();

    // j-chain L1
    {
        f32x4 acc[4];
        #pragma unroll
        for (int ct = 0; ct < 4; ++ct) acc[ct] = (f32x4){0.f, 0.f, 0.f, 0.f};
        #pragma unroll
        for (int s = 0; s < 4; ++s) {
            int k0 = s * 32 + q * 8;
            f16x8 afr = *(const f16x8*)&A1[m][k0];
            #pragma unroll
            for (int ct = 0; ct < 4; ++ct) {
                f16x8 bfr = *(const f16x8*)(Rj1 + ((wv * 4 + ct) * 16 + m) * 128 + k0);
                acc[ct] = MFMA16(afr, bfr, acc[ct]);
            }
        }
        #pragma unroll
        for (int ct = 0; ct < 4; ++ct) {
            int n = (wv * 4 + ct) * 16 + m;
            float bb = bj1[n];
            #pragma unroll
            for (int r = 0; r < 4; ++r)
                A2[q * 4 + r][n] = (f16)fmaxf(acc[ct][r] + bb, 0.f);
        }
    }
    __syncthreads();

    // j-chain L2
    {
        f32x4 acc[2];
        acc[0] = (f32x4){0.f, 0.f, 0.f, 0.f};
        acc[1] = (f32x4){0.f, 0.f, 0.f, 0.f};
        #pragma unroll
        for (int s = 0; s < 8; ++s) {
            int k0 = s * 32 + q * 8;
            f16x8 afr = *(const f16x8*)&A2[m][k0];
            #pragma unroll
            for (int ct = 0; ct < 2; ++ct) {
                f16x8 bfr = *(const f16x8*)(Rj2 + ((wv * 2 + ct) * 16 + m) * 256 + k0);
                acc[ct] = MFMA16(afr, bfr, acc[ct]);
            }
        }
        __syncthreads();
        #pragma unroll
        for (int ct = 0; ct < 2; ++ct) {
            int n = (wv * 2 + ct) * 16 + m;
            float bb = bj2[n];
            #pragma unroll
            for (int r = 0; r < 4; ++r)
                A1[q * 4 + r][n] = (f16)fmaxf(acc[ct][r] + bb, 0.f);
        }
    }
    __syncthreads();

    // j-chain L3 + combine
    if (wv < 2) {
        f32x4 acc = (f32x4){0.f, 0.f, 0.f, 0.f};
        int n = wv * 16 + m;
        #pragma unroll
        for (int s = 0; s < 4; ++s) {
            int k0 = s * 32 + q * 8;
            f16x8 bfr = *(const f16x8*)(Rj3 + n * 128 + k0);
            f16x8 afr = *(const f16x8*)&A1[m][k0];
            acc = MFMA16(afr, bfr, acc);
        }
        float bb = bj3[n];
        #pragma unroll
        for (int r = 0; r < 4; ++r) {
            int row = q * 4 + r;
            int rg = r0 + row;
            int b = rg >> 7, v = rg & 127;
            float maskf = (v < g_size[b]) ? 1.f : 0.f;
            contrib[(size_t)rg * T + n] = maskf * Gl[row][n] * (acc[r] + bb);
        }
    }
}

// -------------------------------------------------------------------------
__global__ __launch_bounds__(64) void finalize_kernel(const float* __restrict__ contrib,
                                                      float* __restrict__ out) {
    __shared__ float res[T];
    int b = blockIdx.x;
    int o = threadIdx.x;
    if (o < T) {
        float s = 0.f;
        for (int v = 0; v < N; ++v) s += contrib[(b * N + v) * T + o];
        res[o] = s;
    }
    __syncthreads();
    if (o < T) {
        float mx = res[0];
        for (int i = 1; i < T; ++i) mx = fmaxf(mx, res[i]);
        float se = 0.f;
        for (int i = 0; i < T; ++i) se += expf(res[i] - mx);
        out[b * T + o] = res[o] - mx - logf(se);
    }
}

// -------------------------------------------------------------------------
extern "C" void kernel_launch(void* const* d_in, const int* in_sizes, int n_in,
                              void* d_out, int out_size, void* d_ws, size_t ws_size,
                              hipStream_t stream) {
    (void)in_sizes; (void)n_in; (void)out_size; (void)ws_size;
    const float* h_in = (const float*)d_in[0];
    const float* am   = (const float*)d_in[1];
    const int*   g_sz = (const int*)d_in[2];
    const float* We0 = (const float*)d_in[3],  *be0 = (const float*)d_in[4];
    const float* We1 = (const float*)d_in[5],  *be1 = (const float*)d_in[6];
    const float* We2 = (const float*)d_in[7],  *be2 = (const float*)d_in[8];
    const float* We3 = (const float*)d_in[9],  *be3 = (const float*)d_in[10];
    const float* Wih = (const float*)d_in[11], *Whh = (const float*)d_in[12];
    const float* bih = (const float*)d_in[13], *bhh = (const float*)d_in[14];
    const float* Wi0 = (const float*)d_in[15], *bi0 = (const float*)d_in[16];
    const float* Wj0 = (const float*)d_in[17], *bj0 = (const float*)d_in[18];
    const float* Wi1 = (const float*)d_in[19], *bi1 = (const float*)d_in[20];
    const float* Wj1 = (const float*)d_in[21], *bj1 = (const float*)d_in[22];
    const float* Wi2 = (const float*)d_in[23], *bi2 = (const float*)d_in[24];
    const float* Wj2 = (const float*)d_in[25], *bj2 = (const float*)d_in[26];
    const float* Wi3 = (const float*)d_in[27], *bi3 = (const float*)d_in[28];
    const float* Wj3 = (const float*)d_in[29], *bj3 = (const float*)d_in[30];

    float* out = (float*)d_out;

    // workspace layout (~110 MB); part f16
    f16*   f    = (f16*)d_ws;                             // 33554432 halves
    f16*   P2   = f + (size_t)33554432;                   // 16777216 halves
    f16*   part = P2 + (size_t)16777216;                  // 4194304 halves
    float* h    = (float*)(part + (size_t)4194304);       // 131072
    float* biasb = h + 131072;                            // 1024
    float* contrib = biasb + 1024;                        // 65536
    f16*   h16  = (f16*)(contrib + 65536);                // 131072 halves
    f16*   hin16 = h16 + 131072;                          // 65536 halves
    f16*   wp   = hin16 + 65536;                          // 749568 halves

    prep_kernel<<<(WPACK_SZ + 255) / 256, 256, 0, stream>>>(
        h_in, We1, We2, We3, Wi0, Wi1, Wi2, Wi3, Wj0, Wj1, Wj2, Wj3,
        h, h16, hin16, wp);

    // layer 0: edge + p_gemm + bias fused into one launch
    mega0_kernel<<<4096 + 1024 + 16, 256, 0, stream>>>(
        am, We0, be0, be1, be2, be3, wp, h, h16, f, P2, biasb);
    msg_mfma<<<dim3(32, 16), 256, 0, stream>>>(f, P2, part);
    gru_kernel<<<B * N, 192, 0, stream>>>(biasb, part, h, h16,
                                          Wih, Whh, bih, bhh, g_sz);

    for (int l = 1; l < 3; ++l) {
        pg_bias_kernel<<<1024 + 16, 256, 0, stream>>>(be3, wp, h, h16, P2, biasb);
        msg_mfma<<<dim3(32, 16), 256, 0, stream>>>(f, P2, part);
        gru_kernel<<<B * N, 192, 0, stream>>>(biasb, part, h, h16,
                                              Wih, Whh, bih, bhh, g_sz);
    }

    readout_mfma<<<128, 256, 0, stream>>>(h16, hin16, g_sz, wp,
                                          bi0, bi1, bi2, bi3,
                                          bj0, bj1, bj2, bj3, contrib);
    finalize_kernel<<<B, 64, 0, stream>>>(contrib, out);
}